// Round 2
// baseline (3733.667 us; speedup 1.0000x reference)
//
#include <hip/hip_runtime.h>
#include <hip/hip_bf16.h>

#define BW 128
#define NTOK 343
#define DIMC 192
#define NHEAD 6
#define HDIM 32
#define TOK (BW * NTOK)      // 43904
#define M2 (2 * TOK)         // 87808
#define NN (NTOK * NTOK)     // 117649

typedef unsigned int uint32;

// round-to-nearest-even f32 -> bf16 bits (values are normal, no NaN expected)
__device__ __forceinline__ unsigned short f2bf(float f) {
  uint32 u = __float_as_uint(f);
  u += 0x7fffu + ((u >> 16) & 1u);
  return (unsigned short)(u >> 16);
}

// 8 packed bf16 (as uint4) -> 8 f32
__device__ __forceinline__ void unpack8(const uint4 v, float* dst) {
  dst[0] = __uint_as_float(v.x << 16);
  dst[1] = __uint_as_float(v.x & 0xffff0000u);
  dst[2] = __uint_as_float(v.y << 16);
  dst[3] = __uint_as_float(v.y & 0xffff0000u);
  dst[4] = __uint_as_float(v.z << 16);
  dst[5] = __uint_as_float(v.z & 0xffff0000u);
  dst[6] = __uint_as_float(v.w << 16);
  dst[7] = __uint_as_float(v.w & 0xffff0000u);
}

// ---------------- bias gather: bias[h][i][j] = rpb[rel_idx[i,j]*NH + h] ----------------
__global__ void k_bias(const float* __restrict__ rpb, const int* __restrict__ ridx,
                       float* __restrict__ biasws) {
  const int idx = blockIdx.x * 256 + threadIdx.x;
  if (idx < NN) {
    const int r = ridx[idx];
#pragma unroll
    for (int h = 0; h < NHEAD; ++h) biasws[h * NN + idx] = rpb[r * NHEAD + h];
  }
}

// ---------------- QKV projection GEMM ----------------
// rows R in [0,87808): stream s = R/TOK, token = R%TOK. cols c in [0,576).
// C[R,c] = dot(X[R,:192], qkv_w[c,:192]) + qkv_b[c]
// scatter bf16 to qkv[s][t][b][h][n][d],  t=c/192, h=(c%192)/32, d=c%32
__global__ __launch_bounds__(256) void k_qkv(const float* __restrict__ x,
                                             const float* __restrict__ x1,
                                             const float* __restrict__ w,
                                             const float* __restrict__ bvec,
                                             __hip_bfloat16* __restrict__ qkvo) {
  __shared__ float Xs[64][193];   // pad 193: bank = (r+k)%32 -> <=2-way (free)
  __shared__ float Ws[64][193];
  const int R0 = blockIdx.x * 64;
  const int C0 = blockIdx.y * 64;
  const int s = R0 / TOK;          // 43904 % 64 == 0, no straddle
  const int tokbase = R0 % TOK;
  const float* __restrict__ src = s ? x1 : x;
  const int tid = threadIdx.x;

  for (int c = tid; c < 64 * 48; c += 256) {
    const int r = c / 48, k4 = (c % 48) * 4;
    const float4 v = *reinterpret_cast<const float4*>(&src[(tokbase + r) * DIMC + k4]);
    Xs[r][k4] = v.x; Xs[r][k4 + 1] = v.y; Xs[r][k4 + 2] = v.z; Xs[r][k4 + 3] = v.w;
  }
  for (int c = tid; c < 64 * 48; c += 256) {
    const int r = c / 48, k4 = (c % 48) * 4;
    const float4 v = *reinterpret_cast<const float4*>(&w[(C0 + r) * DIMC + k4]);
    Ws[r][k4] = v.x; Ws[r][k4 + 1] = v.y; Ws[r][k4 + 2] = v.z; Ws[r][k4 + 3] = v.w;
  }
  __syncthreads();

  const int rg = tid & 15, cg = tid >> 4;   // 16 row-groups x 16 col-groups, 4x4 micro
  float acc[4][4] = {};
#pragma unroll 2
  for (int k = 0; k < DIMC; ++k) {
    float xr[4], wc[4];
#pragma unroll
    for (int i = 0; i < 4; ++i) xr[i] = Xs[rg * 4 + i][k];
#pragma unroll
    for (int j = 0; j < 4; ++j) wc[j] = Ws[cg * 4 + j][k];
#pragma unroll
    for (int i = 0; i < 4; ++i)
#pragma unroll
      for (int j = 0; j < 4; ++j) acc[i][j] = fmaf(xr[i], wc[j], acc[i][j]);
  }

  const int cbase = C0 + cg * 4;            // 4 consecutive cols, same (t,h), d0%4==0
  const int t = cbase / DIMC;
  const int h = (cbase % DIMC) / HDIM;
  const int d0 = cbase % HDIM;
  float bb[4];
#pragma unroll
  for (int j = 0; j < 4; ++j) bb[j] = bvec[cbase + j];
#pragma unroll
  for (int i = 0; i < 4; ++i) {
    const int token = tokbase + rg * 4 + i;
    const int bidx = token / NTOK;
    const int n = token % NTOK;
    const size_t ob =
        ((((size_t)(s * 3 + t) * BW + bidx) * NHEAD + h) * NTOK + n) * HDIM + d0;
    ushort4 pk;
    pk.x = f2bf(acc[i][0] + bb[0]);
    pk.y = f2bf(acc[i][1] + bb[1]);
    pk.z = f2bf(acc[i][2] + bb[2]);
    pk.w = f2bf(acc[i][3] + bb[3]);
    *reinterpret_cast<ushort4*>(&qkvo[ob]) = pk;
  }
}

// ---------------- attention: one block per (s, b, h) ----------------
// q from stream s, k/v from stream 1-s (cross-modal).
__global__ __launch_bounds__(256) void k_attn(const __hip_bfloat16* __restrict__ qkvi,
                                              const float* __restrict__ biasws,
                                              __hip_bfloat16* __restrict__ Ows) {
  __shared__ float Ks[NTOK][34];   // pad 34: 8B-aligned float2, banks spread
  __shared__ float Vs[NTOK][34];
  __shared__ float Ps[4][344];
  const int bid = blockIdx.x;                 // [0, 1536)
  const int s = bid / (BW * NHEAD);
  const int rem = bid % (BW * NHEAD);
  const int b = rem / NHEAD;
  const int h = rem % NHEAD;
  const int so = 1 - s;
  const size_t qbase = (((size_t)(s * 3 + 0) * BW + b) * NHEAD + h) * (size_t)NTOK * HDIM;
  const size_t kbase = (((size_t)(so * 3 + 1) * BW + b) * NHEAD + h) * (size_t)NTOK * HDIM;
  const size_t vbase = (((size_t)(so * 3 + 2) * BW + b) * NHEAD + h) * (size_t)NTOK * HDIM;
  const int tid = threadIdx.x;

  // stage K,V (bf16 -> f32 LDS), 343*32 elems each, 8 bf16 per 16B load
  for (int c = tid; c < NTOK * 4; c += 256) {
    const int n = c >> 2, d0 = (c & 3) * 8;
    float tmp[8];
    unpack8(*reinterpret_cast<const uint4*>(&qkvi[kbase + n * HDIM + d0]), tmp);
#pragma unroll
    for (int e = 0; e < 8; ++e) Ks[n][d0 + e] = tmp[e];
    unpack8(*reinterpret_cast<const uint4*>(&qkvi[vbase + n * HDIM + d0]), tmp);
#pragma unroll
    for (int e = 0; e < 8; ++e) Vs[n][d0 + e] = tmp[e];
  }
  __syncthreads();

  const int w = tid >> 6, lane = tid & 63;
  const float* __restrict__ bh = biasws + (size_t)h * NN;
  const float scale = 0.17677669529663687f;   // 1/sqrt(32)

  for (int t = 0; t < 86; ++t) {
    const int i = t * 4 + w;
    const bool valid = (i < NTOK);            // wave-uniform
    float rsum = 0.f;
    if (valid) {
      float q[32];
      const uint4* q4p = reinterpret_cast<const uint4*>(&qkvi[qbase + i * HDIM]);
#pragma unroll
      for (int u = 0; u < 4; ++u) unpack8(q4p[u], &q[u * 8]);
      const float* brow = bh + i * NTOK;
      float sv[6];
      float m = -1e30f;
#pragma unroll
      for (int jj = 0; jj < 6; ++jj) {
        const int j = jj * 64 + lane;
        float sj = -1e30f;
        if (j < NTOK) {
          float dot = 0.f;
#pragma unroll
          for (int d2 = 0; d2 < 16; ++d2) {
            const float2 kk = *reinterpret_cast<const float2*>(&Ks[j][d2 * 2]);
            dot = fmaf(q[d2 * 2], kk.x, dot);
            dot = fmaf(q[d2 * 2 + 1], kk.y, dot);
          }
          sj = fmaf(dot, scale, brow[j]);
        }
        sv[jj] = sj;
        m = fmaxf(m, sj);
      }
#pragma unroll
      for (int off = 32; off >= 1; off >>= 1) m = fmaxf(m, __shfl_xor(m, off, 64));
      float ssum = 0.f;
#pragma unroll
      for (int jj = 0; jj < 6; ++jj) {
        const int j = jj * 64 + lane;
        if (j < NTOK) {
          const float pv = __expf(sv[jj] - m);
          Ps[w][j] = pv;
          ssum += pv;
        }
      }
#pragma unroll
      for (int off = 32; off >= 1; off >>= 1) ssum += __shfl_xor(ssum, off, 64);
      rsum = 1.f / ssum;
    }
    __syncthreads();   // orders Ps write -> cross-lane read (uniform control flow)

    if (valid) {
      const int dp = lane & 15, qtr = lane >> 4;  // 16 d-pairs x 4 j-quarters
      const int j0 = qtr * 86;
      const int j1 = (j0 + 86 < NTOK) ? (j0 + 86) : NTOK;
      float ox = 0.f, oy = 0.f;
      for (int j = j0; j < j1; ++j) {
        const float pv = Ps[w][j];
        const float2 vv = *reinterpret_cast<const float2*>(&Vs[j][dp * 2]);
        ox = fmaf(pv, vv.x, ox);
        oy = fmaf(pv, vv.y, oy);
      }
      ox += __shfl_xor(ox, 16, 64);
      oy += __shfl_xor(oy, 16, 64);
      ox += __shfl_xor(ox, 32, 64);
      oy += __shfl_xor(oy, 32, 64);
      if (lane < 16) {
        const size_t ob = ((size_t)s * TOK + b * NTOK + i) * DIMC + h * HDIM + dp * 2;
        const uint32 uo = ((uint32)f2bf(oy * rsum) << 16) | (uint32)f2bf(ox * rsum);
        *reinterpret_cast<uint32*>(&Ows[ob]) = uo;
      }
    }
    __syncthreads();
  }
}

// ---------------- output projection GEMM ----------------
// out[R,c] = dot(O[R,:192], proj_w[c,:192]) + proj_b[c], R in [0,87808), c in [0,192)
__global__ __launch_bounds__(256) void k_proj(const __hip_bfloat16* __restrict__ Oin,
                                              const float* __restrict__ w,
                                              const float* __restrict__ pb,
                                              float* __restrict__ out) {
  __shared__ float Xs[64][193];
  __shared__ float Ws[64][193];
  const int R0 = blockIdx.x * 64;
  const int C0 = blockIdx.y * 64;
  const int tid = threadIdx.x;

  for (int c = tid; c < 64 * 24; c += 256) {   // 64*192 bf16 / 8 = 1536 loads
    const int r = c / 24, d8 = (c % 24) * 8;
    float tmp[8];
    unpack8(*reinterpret_cast<const uint4*>(&Oin[(size_t)(R0 + r) * DIMC + d8]), tmp);
#pragma unroll
    for (int e = 0; e < 8; ++e) Xs[r][d8 + e] = tmp[e];
  }
  for (int c = tid; c < 64 * 48; c += 256) {
    const int r = c / 48, k4 = (c % 48) * 4;
    const float4 v = *reinterpret_cast<const float4*>(&w[(C0 + r) * DIMC + k4]);
    Ws[r][k4] = v.x; Ws[r][k4 + 1] = v.y; Ws[r][k4 + 2] = v.z; Ws[r][k4 + 3] = v.w;
  }
  __syncthreads();

  const int rg = tid & 15, cg = tid >> 4;
  float acc[4][4] = {};
#pragma unroll 2
  for (int k = 0; k < DIMC; ++k) {
    float xr[4], wc[4];
#pragma unroll
    for (int i = 0; i < 4; ++i) xr[i] = Xs[rg * 4 + i][k];
#pragma unroll
    for (int j = 0; j < 4; ++j) wc[j] = Ws[cg * 4 + j][k];
#pragma unroll
    for (int i = 0; i < 4; ++i)
#pragma unroll
      for (int j = 0; j < 4; ++j) acc[i][j] = fmaf(xr[i], wc[j], acc[i][j]);
  }

  const int cbase = C0 + cg * 4;
  float bb[4];
#pragma unroll
  for (int j = 0; j < 4; ++j) bb[j] = pb[cbase + j];
#pragma unroll
  for (int i = 0; i < 4; ++i) {
    float4 ov;
    ov.x = acc[i][0] + bb[0];
    ov.y = acc[i][1] + bb[1];
    ov.z = acc[i][2] + bb[2];
    ov.w = acc[i][3] + bb[3];
    *reinterpret_cast<float4*>(&out[(size_t)(R0 + rg * 4 + i) * DIMC + cbase]) = ov;
  }
}

extern "C" void kernel_launch(void* const* d_in, const int* in_sizes, int n_in,
                              void* d_out, int out_size, void* d_ws, size_t ws_size,
                              hipStream_t stream) {
  const float* x      = (const float*)d_in[0];
  const float* x1     = (const float*)d_in[1];
  const float* qkv_w  = (const float*)d_in[2];
  const float* qkv_b  = (const float*)d_in[3];
  const float* proj_w = (const float*)d_in[4];
  const float* proj_b = (const float*)d_in[5];
  const float* rpb    = (const float*)d_in[6];
  const int*   ridx   = (const int*)d_in[7];
  float* out = (float*)d_out;

  // workspace layout:
  //   qkv  bf16 [2][3][B][NH][N][HD] : 50,577,408 elems = 101,154,816 B
  //   O    bf16 [2*TOK][DIM]         : 16,859,136 elems =  33,718,272 B
  //   bias f32  [NH][N][N]           :    705,894 elems =   2,823,576 B
  char* ws = (char*)d_ws;
  __hip_bfloat16* qkv  = (__hip_bfloat16*)ws;
  __hip_bfloat16* Ows  = (__hip_bfloat16*)(ws + 101154816);
  float*          bws  = (float*)(ws + 101154816 + 33718272);

  k_bias<<<(NN + 255) / 256, 256, 0, stream>>>(rpb, ridx, bws);
  k_qkv<<<dim3(M2 / 64, 9), 256, 0, stream>>>(x, x1, qkv_w, qkv_b, qkv);
  k_attn<<<2 * BW * NHEAD, 256, 0, stream>>>(qkv, bws, Ows);
  k_proj<<<dim3(M2 / 64, 3), 256, 0, stream>>>(Ows, proj_w, proj_b, out);
}

// Round 3
// 1228.020 us; speedup vs baseline: 3.0404x; 3.0404x over previous
//
#include <hip/hip_runtime.h>
#include <hip/hip_bf16.h>

#define BW 128
#define NTOK 343
#define DIMC 192
#define NHEAD 6
#define HDIM 32
#define TOK (BW * NTOK)      // 43904
#define M2 (2 * TOK)         // 87808
#define NN (NTOK * NTOK)     // 117649

typedef unsigned int uint32;
typedef __attribute__((ext_vector_type(8))) short short8;   // 8 bf16 = 4 VGPR
typedef __attribute__((ext_vector_type(4))) float f32x4;

// round-to-nearest-even f32 -> bf16 bits
__device__ __forceinline__ unsigned short f2bf(float f) {
  uint32 u = __float_as_uint(f);
  u += 0x7fffu + ((u >> 16) & 1u);
  return (unsigned short)(u >> 16);
}

// 8 packed bf16 (as uint4) -> 8 f32
__device__ __forceinline__ void unpack8(const uint4 v, float* dst) {
  dst[0] = __uint_as_float(v.x << 16);
  dst[1] = __uint_as_float(v.x & 0xffff0000u);
  dst[2] = __uint_as_float(v.y << 16);
  dst[3] = __uint_as_float(v.y & 0xffff0000u);
  dst[4] = __uint_as_float(v.z << 16);
  dst[5] = __uint_as_float(v.z & 0xffff0000u);
  dst[6] = __uint_as_float(v.w << 16);
  dst[7] = __uint_as_float(v.w & 0xffff0000u);
}

// ---------------- bias gather: bias[h][i][j] = rpb[rel_idx[i,j]*NH + h] ----------------
__global__ void k_bias(const float* __restrict__ rpb, const int* __restrict__ ridx,
                       float* __restrict__ biasws) {
  const int idx = blockIdx.x * 256 + threadIdx.x;
  if (idx < NN) {
    const int r = ridx[idx];
#pragma unroll
    for (int h = 0; h < NHEAD; ++h) biasws[h * NN + idx] = rpb[r * NHEAD + h];
  }
}

// ---------------- QKV projection GEMM (f32 VALU; Q pre-scaled) ----------------
__global__ __launch_bounds__(256) void k_qkv(const float* __restrict__ x,
                                             const float* __restrict__ x1,
                                             const float* __restrict__ w,
                                             const float* __restrict__ bvec,
                                             __hip_bfloat16* __restrict__ qkvo) {
  __shared__ float Xs[64][193];
  __shared__ float Ws[64][193];
  const int R0 = blockIdx.x * 64;
  const int C0 = blockIdx.y * 64;
  const int s = R0 / TOK;
  const int tokbase = R0 % TOK;
  const float* __restrict__ src = s ? x1 : x;
  const int tid = threadIdx.x;

  for (int c = tid; c < 64 * 48; c += 256) {
    const int r = c / 48, k4 = (c % 48) * 4;
    const float4 v = *reinterpret_cast<const float4*>(&src[(tokbase + r) * DIMC + k4]);
    Xs[r][k4] = v.x; Xs[r][k4 + 1] = v.y; Xs[r][k4 + 2] = v.z; Xs[r][k4 + 3] = v.w;
  }
  for (int c = tid; c < 64 * 48; c += 256) {
    const int r = c / 48, k4 = (c % 48) * 4;
    const float4 v = *reinterpret_cast<const float4*>(&w[(C0 + r) * DIMC + k4]);
    Ws[r][k4] = v.x; Ws[r][k4 + 1] = v.y; Ws[r][k4 + 2] = v.z; Ws[r][k4 + 3] = v.w;
  }
  __syncthreads();

  const int rg = tid & 15, cg = tid >> 4;
  float acc[4][4] = {};
#pragma unroll 2
  for (int k = 0; k < DIMC; ++k) {
    float xr[4], wc[4];
#pragma unroll
    for (int i = 0; i < 4; ++i) xr[i] = Xs[rg * 4 + i][k];
#pragma unroll
    for (int j = 0; j < 4; ++j) wc[j] = Ws[cg * 4 + j][k];
#pragma unroll
    for (int i = 0; i < 4; ++i)
#pragma unroll
      for (int j = 0; j < 4; ++j) acc[i][j] = fmaf(xr[i], wc[j], acc[i][j]);
  }

  const int cbase = C0 + cg * 4;
  const int t = cbase / DIMC;
  const int h = (cbase % DIMC) / HDIM;
  const int d0 = cbase % HDIM;
  const float qscale = (t == 0) ? 0.17677669529663687f : 1.0f;  // bake softmax scale into Q
  float bb[4];
#pragma unroll
  for (int j = 0; j < 4; ++j) bb[j] = bvec[cbase + j];
#pragma unroll
  for (int i = 0; i < 4; ++i) {
    const int token = tokbase + rg * 4 + i;
    const int bidx = token / NTOK;
    const int n = token % NTOK;
    const size_t ob =
        ((((size_t)(s * 3 + t) * BW + bidx) * NHEAD + h) * NTOK + n) * HDIM + d0;
    ushort4 pk;
    pk.x = f2bf((acc[i][0] + bb[0]) * qscale);
    pk.y = f2bf((acc[i][1] + bb[1]) * qscale);
    pk.z = f2bf((acc[i][2] + bb[2]) * qscale);
    pk.w = f2bf((acc[i][3] + bb[3]) * qscale);
    *reinterpret_cast<ushort4*>(&qkvo[ob]) = pk;
  }
}

// ---------------- MFMA attention: one block per (s,b,h), 4 waves ----------------
// S = Qs·K^T + bias (bias as MFMA C-init); softmax in-register; P via LDS bf16; O = P·V.
__global__ __launch_bounds__(256) void k_attn(const __hip_bfloat16* __restrict__ qkvi,
                                              const float* __restrict__ biasws,
                                              __hip_bfloat16* __restrict__ Ows) {
  // LDS: K bf16 [352][40] (pad 40: start-bank 20r%32 tiles all banks -> conflict-free b128)
  __shared__ unsigned short Ks[352][40];      // 28160 B
  __shared__ unsigned short Vt[32][360];      // 23040 B, V transposed [d][n]
  __shared__ unsigned short Pw[4][16][360];   // 46080 B, per-wave P tile bf16
  const int bid = blockIdx.x;                 // h-major: same-h blocks adjacent (bias L2 reuse)
  const int h = bid / (2 * BW);
  const int sb = bid % (2 * BW);
  const int s = sb >> 7;
  const int b = sb & 127;
  const int so = 1 - s;
  const size_t qbase = (((size_t)(s * 3 + 0) * BW + b) * NHEAD + h) * (size_t)NTOK * HDIM;
  const size_t kbase = (((size_t)(so * 3 + 1) * BW + b) * NHEAD + h) * (size_t)NTOK * HDIM;
  const size_t vbase = (((size_t)(so * 3 + 2) * BW + b) * NHEAD + h) * (size_t)NTOK * HDIM;
  const unsigned short* __restrict__ qp = (const unsigned short*)qkvi;
  unsigned short* __restrict__ op = (unsigned short*)Ows;
  const float* __restrict__ bh = biasws + (size_t)h * NN;
  const int tid = threadIdx.x;

  // ---- stage K (bf16 copy, zero-pad rows 343..351) ----
  for (int idx = tid; idx < 352 * 4; idx += 256) {
    const int n = idx >> 2, d0 = (idx & 3) * 8;
    uint4 v = {0u, 0u, 0u, 0u};
    if (n < NTOK) v = *reinterpret_cast<const uint4*>(qp + kbase + (size_t)n * HDIM + d0);
    *reinterpret_cast<uint4*>(&Ks[n][d0]) = v;
  }
  // ---- stage V transposed ----
  for (int idx = tid; idx < NTOK * 4; idx += 256) {
    const int n = idx >> 2, d0 = (idx & 3) * 8;
    const uint4 v = *reinterpret_cast<const uint4*>(qp + vbase + (size_t)n * HDIM + d0);
    const unsigned short* ep = reinterpret_cast<const unsigned short*>(&v);
#pragma unroll
    for (int e = 0; e < 8; ++e) Vt[d0 + e][n] = ep[e];
  }
  for (int idx = tid; idx < 32 * 9; idx += 256) Vt[idx / 9][NTOK + idx % 9] = 0;
  __syncthreads();

  const int lane = tid & 63, w = tid >> 6;
  const int c16 = lane & 15, q4 = lane >> 4;

  for (int qt = w; qt < 22; qt += 4) {
    // Q A-frag: lane holds Q[qt*16 + c16][q4*8 .. +7] (coalesced 16B global load)
    int qrow = qt * 16 + c16; if (qrow > NTOK - 1) qrow = NTOK - 1;
    const short8 qf = *reinterpret_cast<const short8*>(qp + qbase + (size_t)qrow * HDIM + q4 * 8);

    // acc init = bias (C-in of MFMA); D layout: col=c16, row=q4*4+r
    f32x4 acc[22];
#pragma unroll
    for (int kt = 0; kt < 22; ++kt) {
      const int j = kt * 16 + c16;
      const int jc = (j < NTOK) ? j : NTOK - 1;
      f32x4 a;
#pragma unroll
      for (int r = 0; r < 4; ++r) {
        int i = qt * 16 + q4 * 4 + r; if (i > NTOK - 1) i = NTOK - 1;
        a[r] = bh[i * NTOK + jc];
      }
      acc[kt] = a;
    }
    // QK^T: 22 MFMAs, shared Q frag
#pragma unroll
    for (int kt = 0; kt < 22; ++kt) {
      const short8 kf = *reinterpret_cast<const short8*>(&Ks[kt * 16 + c16][q4 * 8]);
      acc[kt] = __builtin_amdgcn_mfma_f32_16x16x32_bf16(qf, kf, acc[kt], 0, 0, 0);
    }
    // mask invalid cols (kt=21, j>=343 <=> c16>=7)
    if (c16 >= 7) acc[21] = f32x4{-1e30f, -1e30f, -1e30f, -1e30f};

    // softmax per row (row lives in 16 lanes: shfl_xor 1,2,4,8); defer 1/sum to O
    float rs[4];
#pragma unroll
    for (int r = 0; r < 4; ++r) {
      float m = acc[0][r];
#pragma unroll
      for (int kt = 1; kt < 22; ++kt) m = fmaxf(m, acc[kt][r]);
      m = fmaxf(m, __shfl_xor(m, 1, 64));
      m = fmaxf(m, __shfl_xor(m, 2, 64));
      m = fmaxf(m, __shfl_xor(m, 4, 64));
      m = fmaxf(m, __shfl_xor(m, 8, 64));
      float sum = 0.f;
#pragma unroll
      for (int kt = 0; kt < 22; ++kt) {
        const float p = __expf(acc[kt][r] - m);
        acc[kt][r] = p;
        sum += p;
      }
      sum += __shfl_xor(sum, 1, 64);
      sum += __shfl_xor(sum, 2, 64);
      sum += __shfl_xor(sum, 4, 64);
      sum += __shfl_xor(sum, 8, 64);
      rs[r] = 1.f / sum;
    }

    // P -> LDS bf16 (per-wave buffer; 2B writes are 2-way/bank = free)
#pragma unroll
    for (int kt = 0; kt < 22; ++kt) {
#pragma unroll
      for (int r = 0; r < 4; ++r)
        Pw[w][q4 * 4 + r][kt * 16 + c16] = f2bf(acc[kt][r]);
    }

    // O = P·V : A-frag = P row-major, B-frag = V[k][d] via Vt rows (contiguous b128)
    f32x4 o0 = {0.f, 0.f, 0.f, 0.f}, o1 = {0.f, 0.f, 0.f, 0.f};
#pragma unroll
    for (int ks = 0; ks < 11; ++ks) {
      const short8 pf = *reinterpret_cast<const short8*>(&Pw[w][c16][ks * 32 + q4 * 8]);
      const short8 v0 = *reinterpret_cast<const short8*>(&Vt[c16][ks * 32 + q4 * 8]);
      const short8 v1 = *reinterpret_cast<const short8*>(&Vt[16 + c16][ks * 32 + q4 * 8]);
      o0 = __builtin_amdgcn_mfma_f32_16x16x32_bf16(pf, v0, o0, 0, 0, 0);
      o1 = __builtin_amdgcn_mfma_f32_16x16x32_bf16(pf, v1, o1, 0, 0, 0);
    }

    // write O rows (normalize here: 8 mults instead of 343)
#pragma unroll
    for (int r = 0; r < 4; ++r) {
      const int i = qt * 16 + q4 * 4 + r;
      if (i < NTOK) {
        const size_t ob = ((size_t)s * TOK + (size_t)b * NTOK + i) * DIMC + h * HDIM;
        op[ob + c16]      = f2bf(o0[r] * rs[r]);
        op[ob + 16 + c16] = f2bf(o1[r] * rs[r]);
      }
    }
  }
}

// ---------------- output projection GEMM ----------------
__global__ __launch_bounds__(256) void k_proj(const __hip_bfloat16* __restrict__ Oin,
                                              const float* __restrict__ w,
                                              const float* __restrict__ pb,
                                              float* __restrict__ out) {
  __shared__ float Xs[64][193];
  __shared__ float Ws[64][193];
  const int R0 = blockIdx.x * 64;
  const int C0 = blockIdx.y * 64;
  const int tid = threadIdx.x;

  for (int c = tid; c < 64 * 24; c += 256) {
    const int r = c / 24, d8 = (c % 24) * 8;
    float tmp[8];
    unpack8(*reinterpret_cast<const uint4*>(&Oin[(size_t)(R0 + r) * DIMC + d8]), tmp);
#pragma unroll
    for (int e = 0; e < 8; ++e) Xs[r][d8 + e] = tmp[e];
  }
  for (int c = tid; c < 64 * 48; c += 256) {
    const int r = c / 48, k4 = (c % 48) * 4;
    const float4 v = *reinterpret_cast<const float4*>(&w[(C0 + r) * DIMC + k4]);
    Ws[r][k4] = v.x; Ws[r][k4 + 1] = v.y; Ws[r][k4 + 2] = v.z; Ws[r][k4 + 3] = v.w;
  }
  __syncthreads();

  const int rg = tid & 15, cg = tid >> 4;
  float acc[4][4] = {};
#pragma unroll 2
  for (int k = 0; k < DIMC; ++k) {
    float xr[4], wc[4];
#pragma unroll
    for (int i = 0; i < 4; ++i) xr[i] = Xs[rg * 4 + i][k];
#pragma unroll
    for (int j = 0; j < 4; ++j) wc[j] = Ws[cg * 4 + j][k];
#pragma unroll
    for (int i = 0; i < 4; ++i)
#pragma unroll
      for (int j = 0; j < 4; ++j) acc[i][j] = fmaf(xr[i], wc[j], acc[i][j]);
  }

  const int cbase = C0 + cg * 4;
  float bb[4];
#pragma unroll
  for (int j = 0; j < 4; ++j) bb[j] = pb[cbase + j];
#pragma unroll
  for (int i = 0; i < 4; ++i) {
    float4 ov;
    ov.x = acc[i][0] + bb[0];
    ov.y = acc[i][1] + bb[1];
    ov.z = acc[i][2] + bb[2];
    ov.w = acc[i][3] + bb[3];
    *reinterpret_cast<float4*>(&out[(size_t)(R0 + rg * 4 + i) * DIMC + cbase]) = ov;
  }
}

extern "C" void kernel_launch(void* const* d_in, const int* in_sizes, int n_in,
                              void* d_out, int out_size, void* d_ws, size_t ws_size,
                              hipStream_t stream) {
  const float* x      = (const float*)d_in[0];
  const float* x1     = (const float*)d_in[1];
  const float* qkv_w  = (const float*)d_in[2];
  const float* qkv_b  = (const float*)d_in[3];
  const float* proj_w = (const float*)d_in[4];
  const float* proj_b = (const float*)d_in[5];
  const float* rpb    = (const float*)d_in[6];
  const int*   ridx   = (const int*)d_in[7];
  float* out = (float*)d_out;

  // workspace: qkv bf16 101,154,816 B | O bf16 33,718,272 B | bias f32 2,823,576 B
  char* ws = (char*)d_ws;
  __hip_bfloat16* qkv  = (__hip_bfloat16*)ws;
  __hip_bfloat16* Ows  = (__hip_bfloat16*)(ws + 101154816);
  float*          bws  = (float*)(ws + 101154816 + 33718272);

  k_bias<<<(NN + 255) / 256, 256, 0, stream>>>(rpb, ridx, bws);
  k_qkv<<<dim3(M2 / 64, 9), 256, 0, stream>>>(x, x1, qkv_w, qkv_b, qkv);
  k_attn<<<2 * BW * NHEAD, 256, 0, stream>>>(qkv, bws, Ows);
  k_proj<<<dim3(M2 / 64, 3), 256, 0, stream>>>(Ows, proj_w, proj_b, out);
}

// Round 4
// 294.502 us; speedup vs baseline: 12.6779x; 4.1698x over previous
//
#include <hip/hip_runtime.h>
#include <hip/hip_bf16.h>

#define BW 128
#define NTOK 343
#define DIMC 192
#define NHEAD 6
#define HDIM 32
#define TOK (BW * NTOK)      // 43904
#define M2 (2 * TOK)         // 87808
#define NN (NTOK * NTOK)     // 117649
#define QSCALE 0.17677669529663687f

typedef unsigned int uint32;
typedef __attribute__((ext_vector_type(8))) short short8;   // 8 bf16 = 4 VGPR
typedef __attribute__((ext_vector_type(4))) float f32x4;

// round-to-nearest-even f32 -> bf16 bits
__device__ __forceinline__ unsigned short f2bf(float f) {
  uint32 u = __float_as_uint(f);
  u += 0x7fffu + ((u >> 16) & 1u);
  return (unsigned short)(u >> 16);
}

__device__ __forceinline__ uint4 pack8bf(const float4 a, const float4 b) {
  uint4 pk;
  pk.x = (uint32)f2bf(a.x) | ((uint32)f2bf(a.y) << 16);
  pk.y = (uint32)f2bf(a.z) | ((uint32)f2bf(a.w) << 16);
  pk.z = (uint32)f2bf(b.x) | ((uint32)f2bf(b.y) << 16);
  pk.w = (uint32)f2bf(b.z) | ((uint32)f2bf(b.w) << 16);
  return pk;
}

// ---------------- bias gather: bias[h][i][j] = rpb[rel_idx[i,j]*NH + h] ----------------
__global__ void k_bias(const float* __restrict__ rpb, const int* __restrict__ ridx,
                       float* __restrict__ biasws) {
  const int idx = blockIdx.x * 256 + threadIdx.x;
  if (idx < NN) {
    const int r = ridx[idx];
#pragma unroll
    for (int h = 0; h < NHEAD; ++h) biasws[h * NN + idx] = rpb[r * NHEAD + h];
  }
}

// ---------------- QKV projection: MFMA bf16, 64-row blocks, 9 col-tiles looped ----------------
// C[row, col] = dot(X[row,:192], W[col,:192]) + b[col];  mfma(Xfrag, Wfrag) = X·W^T directly.
__global__ __launch_bounds__(256) void k_qkv(const float* __restrict__ x,
                                             const float* __restrict__ x1,
                                             const float* __restrict__ w,
                                             const float* __restrict__ bvec,
                                             unsigned short* __restrict__ qkvo) {
  __shared__ unsigned short Xs[64][200];   // 25.6 KB, stride 400B: frag reads spread 8 chunk-classes
  __shared__ unsigned short Ws[64][200];
  const int R0 = blockIdx.x * 64;
  const int s = R0 / TOK;
  const int tokbase = R0 % TOK;
  const float* __restrict__ src = s ? x1 : x;
  const int tid = threadIdx.x;
  const int lane = tid & 63, wv = tid >> 6;
  const int c16 = lane & 15, q4 = lane >> 4;
  const int wr = wv >> 1, wc = wv & 1;     // 2x2 wave grid, 32x32 per wave

  // stage X (f32 -> bf16), each row read from HBM exactly once
  for (int c = tid; c < 64 * 24; c += 256) {
    const int r = c / 24, k8 = (c % 24) * 8;
    const float* p = &src[(size_t)(tokbase + r) * DIMC + k8];
    const float4 a = *reinterpret_cast<const float4*>(p);
    const float4 b = *reinterpret_cast<const float4*>(p + 4);
    *reinterpret_cast<uint4*>(&Xs[r][k8]) = pack8bf(a, b);
  }

  for (int ct = 0; ct < 9; ++ct) {
    __syncthreads();   // prev-iter Ws reads done (also covers X-stage -> first use)
    for (int c = tid; c < 64 * 24; c += 256) {
      const int r = c / 24, k8 = (c % 24) * 8;
      const float* p = &w[(size_t)(ct * 64 + r) * DIMC + k8];
      const float4 a = *reinterpret_cast<const float4*>(p);
      const float4 b = *reinterpret_cast<const float4*>(p + 4);
      *reinterpret_cast<uint4*>(&Ws[r][k8]) = pack8bf(a, b);
    }
    __syncthreads();

    const int colbase = ct * 64 + wc * 32;
    f32x4 acc[2][2];
#pragma unroll
    for (int n = 0; n < 2; ++n) {
      const float bv = bvec[colbase + n * 16 + c16];
      acc[0][n] = f32x4{bv, bv, bv, bv};
      acc[1][n] = f32x4{bv, bv, bv, bv};
    }
#pragma unroll
    for (int ks = 0; ks < 6; ++ks) {
      const short8 a0 = *reinterpret_cast<const short8*>(&Xs[wr * 32 + c16][ks * 32 + q4 * 8]);
      const short8 a1 = *reinterpret_cast<const short8*>(&Xs[wr * 32 + 16 + c16][ks * 32 + q4 * 8]);
      const short8 b0 = *reinterpret_cast<const short8*>(&Ws[wc * 32 + c16][ks * 32 + q4 * 8]);
      const short8 b1 = *reinterpret_cast<const short8*>(&Ws[wc * 32 + 16 + c16][ks * 32 + q4 * 8]);
      acc[0][0] = __builtin_amdgcn_mfma_f32_16x16x32_bf16(a0, b0, acc[0][0], 0, 0, 0);
      acc[0][1] = __builtin_amdgcn_mfma_f32_16x16x32_bf16(a0, b1, acc[0][1], 0, 0, 0);
      acc[1][0] = __builtin_amdgcn_mfma_f32_16x16x32_bf16(a1, b0, acc[1][0], 0, 0, 0);
      acc[1][1] = __builtin_amdgcn_mfma_f32_16x16x32_bf16(a1, b1, acc[1][1], 0, 0, 0);
    }

    // epilogue: D[col=c16-part, row=q4*4+r]; scatter bf16 to qkv[s][t][b][h][n][d]
#pragma unroll
    for (int n = 0; n < 2; ++n) {
      const int col = colbase + n * 16 + c16;
      const int t = col / DIMC;
      const int h = (col % DIMC) / HDIM;
      const int d = col % HDIM;
      const float qs = (t == 0) ? QSCALE : 1.0f;
#pragma unroll
      for (int m = 0; m < 2; ++m) {
#pragma unroll
        for (int r = 0; r < 4; ++r) {
          const int token = tokbase + wr * 32 + m * 16 + q4 * 4 + r;
          const int bidx = token / NTOK;
          const int nn = token % NTOK;
          const size_t ob =
              ((((size_t)(s * 3 + t) * BW + bidx) * NHEAD + h) * NTOK + nn) * HDIM + d;
          qkvo[ob] = f2bf(acc[m][n][r] * qs);
        }
      }
    }
  }
}

// ---------------- MFMA attention: one block per (s,b,h), 4 waves (unchanged, proven) ----------------
__global__ __launch_bounds__(256) void k_attn(const __hip_bfloat16* __restrict__ qkvi,
                                              const float* __restrict__ biasws,
                                              __hip_bfloat16* __restrict__ Ows) {
  __shared__ unsigned short Ks[352][40];      // 28160 B
  __shared__ unsigned short Vt[32][360];      // 23040 B, V transposed [d][n]
  __shared__ unsigned short Pw[4][16][360];   // 46080 B, per-wave P tile bf16
  const int bid = blockIdx.x;
  const int h = bid / (2 * BW);
  const int sb = bid % (2 * BW);
  const int s = sb >> 7;
  const int b = sb & 127;
  const int so = 1 - s;
  const size_t qbase = (((size_t)(s * 3 + 0) * BW + b) * NHEAD + h) * (size_t)NTOK * HDIM;
  const size_t kbase = (((size_t)(so * 3 + 1) * BW + b) * NHEAD + h) * (size_t)NTOK * HDIM;
  const size_t vbase = (((size_t)(so * 3 + 2) * BW + b) * NHEAD + h) * (size_t)NTOK * HDIM;
  const unsigned short* __restrict__ qp = (const unsigned short*)qkvi;
  unsigned short* __restrict__ op = (unsigned short*)Ows;
  const float* __restrict__ bh = biasws + (size_t)h * NN;
  const int tid = threadIdx.x;

  for (int idx = tid; idx < 352 * 4; idx += 256) {
    const int n = idx >> 2, d0 = (idx & 3) * 8;
    uint4 v = {0u, 0u, 0u, 0u};
    if (n < NTOK) v = *reinterpret_cast<const uint4*>(qp + kbase + (size_t)n * HDIM + d0);
    *reinterpret_cast<uint4*>(&Ks[n][d0]) = v;
  }
  for (int idx = tid; idx < NTOK * 4; idx += 256) {
    const int n = idx >> 2, d0 = (idx & 3) * 8;
    const uint4 v = *reinterpret_cast<const uint4*>(qp + vbase + (size_t)n * HDIM + d0);
    const unsigned short* ep = reinterpret_cast<const unsigned short*>(&v);
#pragma unroll
    for (int e = 0; e < 8; ++e) Vt[d0 + e][n] = ep[e];
  }
  for (int idx = tid; idx < 32 * 9; idx += 256) Vt[idx / 9][NTOK + idx % 9] = 0;
  __syncthreads();

  const int lane = tid & 63, w = tid >> 6;
  const int c16 = lane & 15, q4 = lane >> 4;

  for (int qt = w; qt < 22; qt += 4) {
    int qrow = qt * 16 + c16; if (qrow > NTOK - 1) qrow = NTOK - 1;
    const short8 qf = *reinterpret_cast<const short8*>(qp + qbase + (size_t)qrow * HDIM + q4 * 8);

    f32x4 acc[22];
#pragma unroll
    for (int kt = 0; kt < 22; ++kt) {
      const int j = kt * 16 + c16;
      const int jc = (j < NTOK) ? j : NTOK - 1;
      f32x4 a;
#pragma unroll
      for (int r = 0; r < 4; ++r) {
        int i = qt * 16 + q4 * 4 + r; if (i > NTOK - 1) i = NTOK - 1;
        a[r] = bh[i * NTOK + jc];
      }
      acc[kt] = a;
    }
#pragma unroll
    for (int kt = 0; kt < 22; ++kt) {
      const short8 kf = *reinterpret_cast<const short8*>(&Ks[kt * 16 + c16][q4 * 8]);
      acc[kt] = __builtin_amdgcn_mfma_f32_16x16x32_bf16(qf, kf, acc[kt], 0, 0, 0);
    }
    if (c16 >= 7) acc[21] = f32x4{-1e30f, -1e30f, -1e30f, -1e30f};

    float rs[4];
#pragma unroll
    for (int r = 0; r < 4; ++r) {
      float m = acc[0][r];
#pragma unroll
      for (int kt = 1; kt < 22; ++kt) m = fmaxf(m, acc[kt][r]);
      m = fmaxf(m, __shfl_xor(m, 1, 64));
      m = fmaxf(m, __shfl_xor(m, 2, 64));
      m = fmaxf(m, __shfl_xor(m, 4, 64));
      m = fmaxf(m, __shfl_xor(m, 8, 64));
      float sum = 0.f;
#pragma unroll
      for (int kt = 0; kt < 22; ++kt) {
        const float p = __expf(acc[kt][r] - m);
        acc[kt][r] = p;
        sum += p;
      }
      sum += __shfl_xor(sum, 1, 64);
      sum += __shfl_xor(sum, 2, 64);
      sum += __shfl_xor(sum, 4, 64);
      sum += __shfl_xor(sum, 8, 64);
      rs[r] = 1.f / sum;
    }

#pragma unroll
    for (int kt = 0; kt < 22; ++kt) {
#pragma unroll
      for (int r = 0; r < 4; ++r)
        Pw[w][q4 * 4 + r][kt * 16 + c16] = f2bf(acc[kt][r]);
    }

    f32x4 o0 = {0.f, 0.f, 0.f, 0.f}, o1 = {0.f, 0.f, 0.f, 0.f};
#pragma unroll
    for (int ks = 0; ks < 11; ++ks) {
      const short8 pf = *reinterpret_cast<const short8*>(&Pw[w][c16][ks * 32 + q4 * 8]);
      const short8 v0 = *reinterpret_cast<const short8*>(&Vt[c16][ks * 32 + q4 * 8]);
      const short8 v1 = *reinterpret_cast<const short8*>(&Vt[16 + c16][ks * 32 + q4 * 8]);
      o0 = __builtin_amdgcn_mfma_f32_16x16x32_bf16(pf, v0, o0, 0, 0, 0);
      o1 = __builtin_amdgcn_mfma_f32_16x16x32_bf16(pf, v1, o1, 0, 0, 0);
    }

#pragma unroll
    for (int r = 0; r < 4; ++r) {
      const int i = qt * 16 + q4 * 4 + r;
      if (i < NTOK) {
        const size_t ob = ((size_t)s * TOK + (size_t)b * NTOK + i) * DIMC + h * HDIM;
        op[ob + c16]      = f2bf(o0[r] * rs[r]);
        op[ob + 16 + c16] = f2bf(o1[r] * rs[r]);
      }
    }
  }
}

// ---------------- output projection: MFMA bf16, 64-row blocks, 3 col-tiles ----------------
__global__ __launch_bounds__(256) void k_proj(const unsigned short* __restrict__ Oin,
                                              const float* __restrict__ w,
                                              const float* __restrict__ pb,
                                              float* __restrict__ out) {
  __shared__ unsigned short Xs[64][200];
  __shared__ unsigned short Ws[64][200];
  const int R0 = blockIdx.x * 64;
  const int tid = threadIdx.x;
  const int lane = tid & 63, wv = tid >> 6;
  const int c16 = lane & 15, q4 = lane >> 4;
  const int wr = wv >> 1, wc = wv & 1;

  // stage O rows (already bf16): plain 16B copies
  for (int c = tid; c < 64 * 24; c += 256) {
    const int r = c / 24, k8 = (c % 24) * 8;
    *reinterpret_cast<uint4*>(&Xs[r][k8]) =
        *reinterpret_cast<const uint4*>(&Oin[(size_t)(R0 + r) * DIMC + k8]);
  }

  for (int ct = 0; ct < 3; ++ct) {
    __syncthreads();
    for (int c = tid; c < 64 * 24; c += 256) {
      const int r = c / 24, k8 = (c % 24) * 8;
      const float* p = &w[(size_t)(ct * 64 + r) * DIMC + k8];
      const float4 a = *reinterpret_cast<const float4*>(p);
      const float4 b = *reinterpret_cast<const float4*>(p + 4);
      *reinterpret_cast<uint4*>(&Ws[r][k8]) = pack8bf(a, b);
    }
    __syncthreads();

    const int colbase = ct * 64 + wc * 32;
    f32x4 acc[2][2];
#pragma unroll
    for (int n = 0; n < 2; ++n) {
      const float bv = pb[colbase + n * 16 + c16];
      acc[0][n] = f32x4{bv, bv, bv, bv};
      acc[1][n] = f32x4{bv, bv, bv, bv};
    }
#pragma unroll
    for (int ks = 0; ks < 6; ++ks) {
      const short8 a0 = *reinterpret_cast<const short8*>(&Xs[wr * 32 + c16][ks * 32 + q4 * 8]);
      const short8 a1 = *reinterpret_cast<const short8*>(&Xs[wr * 32 + 16 + c16][ks * 32 + q4 * 8]);
      const short8 b0 = *reinterpret_cast<const short8*>(&Ws[wc * 32 + c16][ks * 32 + q4 * 8]);
      const short8 b1 = *reinterpret_cast<const short8*>(&Ws[wc * 32 + 16 + c16][ks * 32 + q4 * 8]);
      acc[0][0] = __builtin_amdgcn_mfma_f32_16x16x32_bf16(a0, b0, acc[0][0], 0, 0, 0);
      acc[0][1] = __builtin_amdgcn_mfma_f32_16x16x32_bf16(a0, b1, acc[0][1], 0, 0, 0);
      acc[1][0] = __builtin_amdgcn_mfma_f32_16x16x32_bf16(a1, b0, acc[1][0], 0, 0, 0);
      acc[1][1] = __builtin_amdgcn_mfma_f32_16x16x32_bf16(a1, b1, acc[1][1], 0, 0, 0);
    }

#pragma unroll
    for (int m = 0; m < 2; ++m) {
#pragma unroll
      for (int n = 0; n < 2; ++n) {
        const int col = colbase + n * 16 + c16;
#pragma unroll
        for (int r = 0; r < 4; ++r) {
          const int row = R0 + wr * 32 + m * 16 + q4 * 4 + r;
          out[(size_t)row * DIMC + col] = acc[m][n][r];
        }
      }
    }
  }
}

extern "C" void kernel_launch(void* const* d_in, const int* in_sizes, int n_in,
                              void* d_out, int out_size, void* d_ws, size_t ws_size,
                              hipStream_t stream) {
  const float* x      = (const float*)d_in[0];
  const float* x1     = (const float*)d_in[1];
  const float* qkv_w  = (const float*)d_in[2];
  const float* qkv_b  = (const float*)d_in[3];
  const float* proj_w = (const float*)d_in[4];
  const float* proj_b = (const float*)d_in[5];
  const float* rpb    = (const float*)d_in[6];
  const int*   ridx   = (const int*)d_in[7];
  float* out = (float*)d_out;

  // workspace: qkv bf16 101,154,816 B | O bf16 33,718,272 B | bias f32 2,823,576 B
  char* ws = (char*)d_ws;
  unsigned short* qkv  = (unsigned short*)ws;
  unsigned short* Ows  = (unsigned short*)(ws + 101154816);
  float*          bws  = (float*)(ws + 101154816 + 33718272);

  k_bias<<<(NN + 255) / 256, 256, 0, stream>>>(rpb, ridx, bws);
  k_qkv<<<M2 / 64, 256, 0, stream>>>(x, x1, qkv_w, qkv_b, qkv);
  k_attn<<<2 * BW * NHEAD, 256, 0, stream>>>((const __hip_bfloat16*)qkv, bws,
                                             (__hip_bfloat16*)Ows);
  k_proj<<<M2 / 64, 256, 0, stream>>>(Ows, proj_w, proj_b, out);
}

// Round 8
// 269.096 us; speedup vs baseline: 13.8748x; 1.0944x over previous
//
#include <hip/hip_runtime.h>
#include <hip/hip_bf16.h>

#define BW 128
#define NTOK 343
#define DIMC 192
#define NHEAD 6
#define HDIM 32
#define TOK (BW * NTOK)      // 43904
#define M2 (2 * TOK)         // 87808
#define NN (NTOK * NTOK)     // 117649
#define BSTR 344             // padded bias row stride (16B-aligned float4 reads)
#define BNN (NTOK * BSTR)    // 117992 per head
#define QSCALE 0.17677669529663687f

typedef unsigned int uint32;
typedef __attribute__((ext_vector_type(8))) short short8;   // 8 bf16 = 4 VGPR
typedef __attribute__((ext_vector_type(4))) float f32x4;

// round-to-nearest-even f32 -> bf16 bits
__device__ __forceinline__ unsigned short f2bf(float f) {
  uint32 u = __float_as_uint(f);
  u += 0x7fffu + ((u >> 16) & 1u);
  return (unsigned short)(u >> 16);
}

__device__ __forceinline__ uint32 pkpair(float a, float b) {
  return (uint32)f2bf(a) | ((uint32)f2bf(b) << 16);
}

__device__ __forceinline__ uint4 pack8bf(const float4 a, const float4 b) {
  uint4 pk;
  pk.x = pkpair(a.x, a.y);
  pk.y = pkpair(a.z, a.w);
  pk.z = pkpair(b.x, b.y);
  pk.w = pkpair(b.z, b.w);
  return pk;
}

// ---------------- bias gather: bias[h][i][j] = rpb[rel_idx[i,j]*NH + h], row stride 344 ----------------
__global__ void k_bias(const float* __restrict__ rpb, const int* __restrict__ ridx,
                       float* __restrict__ biasws) {
  const int idx = blockIdx.x * 256 + threadIdx.x;
  if (idx < NN) {
    const int r = ridx[idx];
    const int i = idx / NTOK, j = idx % NTOK;
#pragma unroll
    for (int h = 0; h < NHEAD; ++h) biasws[h * BNN + i * BSTR + j] = rpb[r * NHEAD + h];
  }
}

// ---------------- QKV projection: MFMA bf16, 64-row blocks, 9 col-tiles looped ----------------
__global__ __launch_bounds__(256) void k_qkv(const float* __restrict__ x,
                                             const float* __restrict__ x1,
                                             const float* __restrict__ w,
                                             const float* __restrict__ bvec,
                                             unsigned short* __restrict__ qkvo) {
  __shared__ unsigned short Xs[64][200];
  __shared__ unsigned short Ws[64][200];
  const int R0 = blockIdx.x * 64;
  const int s = R0 / TOK;
  const int tokbase = R0 % TOK;
  const float* __restrict__ src = s ? x1 : x;
  const int tid = threadIdx.x;
  const int lane = tid & 63, wv = tid >> 6;
  const int c16 = lane & 15, q4 = lane >> 4;
  const int wr = wv >> 1, wc = wv & 1;

  for (int c = tid; c < 64 * 24; c += 256) {
    const int r = c / 24, k8 = (c % 24) * 8;
    const float* p = &src[(size_t)(tokbase + r) * DIMC + k8];
    const float4 a = *reinterpret_cast<const float4*>(p);
    const float4 b = *reinterpret_cast<const float4*>(p + 4);
    *reinterpret_cast<uint4*>(&Xs[r][k8]) = pack8bf(a, b);
  }

  for (int ct = 0; ct < 9; ++ct) {
    __syncthreads();
    for (int c = tid; c < 64 * 24; c += 256) {
      const int r = c / 24, k8 = (c % 24) * 8;
      const float* p = &w[(size_t)(ct * 64 + r) * DIMC + k8];
      const float4 a = *reinterpret_cast<const float4*>(p);
      const float4 b = *reinterpret_cast<const float4*>(p + 4);
      *reinterpret_cast<uint4*>(&Ws[r][k8]) = pack8bf(a, b);
    }
    __syncthreads();

    const int colbase = ct * 64 + wc * 32;
    f32x4 acc[2][2];
#pragma unroll
    for (int n = 0; n < 2; ++n) {
      const float bv = bvec[colbase + n * 16 + c16];
      acc[0][n] = f32x4{bv, bv, bv, bv};
      acc[1][n] = f32x4{bv, bv, bv, bv};
    }
#pragma unroll
    for (int ks = 0; ks < 6; ++ks) {
      const short8 a0 = *reinterpret_cast<const short8*>(&Xs[wr * 32 + c16][ks * 32 + q4 * 8]);
      const short8 a1 = *reinterpret_cast<const short8*>(&Xs[wr * 32 + 16 + c16][ks * 32 + q4 * 8]);
      const short8 b0 = *reinterpret_cast<const short8*>(&Ws[wc * 32 + c16][ks * 32 + q4 * 8]);
      const short8 b1 = *reinterpret_cast<const short8*>(&Ws[wc * 32 + 16 + c16][ks * 32 + q4 * 8]);
      acc[0][0] = __builtin_amdgcn_mfma_f32_16x16x32_bf16(a0, b0, acc[0][0], 0, 0, 0);
      acc[0][1] = __builtin_amdgcn_mfma_f32_16x16x32_bf16(a0, b1, acc[0][1], 0, 0, 0);
      acc[1][0] = __builtin_amdgcn_mfma_f32_16x16x32_bf16(a1, b0, acc[1][0], 0, 0, 0);
      acc[1][1] = __builtin_amdgcn_mfma_f32_16x16x32_bf16(a1, b1, acc[1][1], 0, 0, 0);
    }

#pragma unroll
    for (int n = 0; n < 2; ++n) {
      const int col = colbase + n * 16 + c16;
      const int t = col / DIMC;
      const int h = (col % DIMC) / HDIM;
      const int d = col % HDIM;
      const float qs = (t == 0) ? QSCALE : 1.0f;
#pragma unroll
      for (int m = 0; m < 2; ++m) {
#pragma unroll
        for (int r = 0; r < 4; ++r) {
          const int token = tokbase + wr * 32 + m * 16 + q4 * 4 + r;
          const int bidx = token / NTOK;
          const int nn = token % NTOK;
          const size_t ob =
              ((((size_t)(s * 3 + t) * BW + bidx) * NHEAD + h) * NTOK + nn) * HDIM + d;
          qkvo[ob] = f2bf(acc[m][n][r] * qs);
        }
      }
    }
  }
}

// ---------------- MFMA attention, swapped QK^T: lane owns a softmax row in registers ----------------
// S^T via mfma(K,Q): lane(c16,q4) holds S[i=qt*16+c16][j=kt*16+q4*4+r] in acc[kt][r].
// No P LDS round-trip: P->A-frag via pack + 8 shfl per k-slot. LDS = K + Vt only (51.2 KB).
__global__ __launch_bounds__(256) void k_attn(const __hip_bfloat16* __restrict__ qkvi,
                                              const float* __restrict__ biasws,
                                              __hip_bfloat16* __restrict__ Ows) {
  __shared__ unsigned short Ks[352][40];      // 28160 B
  __shared__ unsigned short Vt[32][360];      // 23040 B, V transposed [d][n]
  const int bid = blockIdx.x;
  const int h = bid / (2 * BW);
  const int sb = bid % (2 * BW);
  const int s = sb >> 7;
  const int b = sb & 127;
  const int so = 1 - s;
  const size_t qbase = (((size_t)(s * 3 + 0) * BW + b) * NHEAD + h) * (size_t)NTOK * HDIM;
  const size_t kbase = (((size_t)(so * 3 + 1) * BW + b) * NHEAD + h) * (size_t)NTOK * HDIM;
  const size_t vbase = (((size_t)(so * 3 + 2) * BW + b) * NHEAD + h) * (size_t)NTOK * HDIM;
  const unsigned short* __restrict__ qp = (const unsigned short*)qkvi;
  unsigned short* __restrict__ op = (unsigned short*)Ows;
  const float* __restrict__ bh = biasws + (size_t)h * BNN;
  const int tid = threadIdx.x;

  for (int idx = tid; idx < 352 * 4; idx += 256) {
    const int n = idx >> 2, d0 = (idx & 3) * 8;
    uint4 v = {0u, 0u, 0u, 0u};
    if (n < NTOK) v = *reinterpret_cast<const uint4*>(qp + kbase + (size_t)n * HDIM + d0);
    *reinterpret_cast<uint4*>(&Ks[n][d0]) = v;
  }
  for (int idx = tid; idx < NTOK * 4; idx += 256) {
    const int n = idx >> 2, d0 = (idx & 3) * 8;
    const uint4 v = *reinterpret_cast<const uint4*>(qp + vbase + (size_t)n * HDIM + d0);
    const unsigned short* ep = reinterpret_cast<const unsigned short*>(&v);
#pragma unroll
    for (int e = 0; e < 8; ++e) Vt[d0 + e][n] = ep[e];
  }
  for (int idx = tid; idx < 32 * 9; idx += 256) Vt[idx / 9][NTOK + idx % 9] = 0;
  __syncthreads();

  const int lane = tid & 63, w = tid >> 6;
  const int c16 = lane & 15, q4 = lane >> 4;
  const int srcA = c16 + ((q4 & 1) << 5);   // source lane group 2*(q4&1)
  const int srcB = srcA + 16;               // source lane group 2*(q4&1)+1
  const bool loSel = (q4 < 2);              // kt parity select: even for q4<2

  for (int qt = w; qt < 22; qt += 4) {
    const int iq = qt * 16 + c16;                     // this lane's softmax row
    const int iqc = (iq < NTOK) ? iq : NTOK - 1;      // clamp (dup rows masked by O-write)
    const short8 qf = *reinterpret_cast<const short8*>(qp + qbase + (size_t)iqc * HDIM + q4 * 8);

    // C-init = bias[iqc][kt*16 + q4*4 ..+3] (aligned float4; kt=21 clamped, masked below)
    f32x4 acc[22];
    const float* brow = bh + (size_t)iqc * BSTR;
#pragma unroll
    for (int kt = 0; kt < 22; ++kt) {
      const int jb = (kt < 21) ? (kt * 16 + q4 * 4) : (336 + (loSel ? q4 * 4 : 0));
      const float4 bv = *reinterpret_cast<const float4*>(brow + jb);
      acc[kt] = f32x4{bv.x, bv.y, bv.z, bv.w};
    }
    // swapped QK^T: 22 MFMAs
#pragma unroll
    for (int kt = 0; kt < 22; ++kt) {
      const short8 kf = *reinterpret_cast<const short8*>(&Ks[kt * 16 + c16][q4 * 8]);
      acc[kt] = __builtin_amdgcn_mfma_f32_16x16x32_bf16(kf, qf, acc[kt], 0, 0, 0);
    }
    // mask invalid j: kt=21, j = 336 + q4*4 + r >= 343
#pragma unroll
    for (int r = 0; r < 4; ++r)
      if (q4 * 4 + r >= 7) acc[21][r] = -1e30f;

    // row softmax fully in-register: own 88 values + 2 shuffles
    float m = acc[0][0];
#pragma unroll
    for (int kt = 0; kt < 22; ++kt)
#pragma unroll
      for (int r = 0; r < 4; ++r) m = fmaxf(m, acc[kt][r]);
    m = fmaxf(m, __shfl_xor(m, 16, 64));
    m = fmaxf(m, __shfl_xor(m, 32, 64));
    float sum = 0.f;
#pragma unroll
    for (int kt = 0; kt < 22; ++kt)
#pragma unroll
      for (int r = 0; r < 4; ++r) {
        const float p = __expf(acc[kt][r] - m);
        acc[kt][r] = p;
        sum += p;
      }
    sum += __shfl_xor(sum, 16, 64);
    sum += __shfl_xor(sum, 32, 64);
    const float rinv = 1.f / sum;

    // PV: per k-slot assemble P A-frag (pack + 8 shfl + 4 sel), 2 MFMAs
    f32x4 o0 = {0.f, 0.f, 0.f, 0.f}, o1 = {0.f, 0.f, 0.f, 0.f};
#pragma unroll
    for (int ks = 0; ks < 11; ++ks) {
      const uint32 e0 = pkpair(acc[2 * ks][0], acc[2 * ks][1]);
      const uint32 e1 = pkpair(acc[2 * ks][2], acc[2 * ks][3]);
      const uint32 d0 = pkpair(acc[2 * ks + 1][0], acc[2 * ks + 1][1]);
      const uint32 d1 = pkpair(acc[2 * ks + 1][2], acc[2 * ks + 1][3]);
      const uint32 a0e = (uint32)__shfl((int)e0, srcA, 64);
      const uint32 a0o = (uint32)__shfl((int)d0, srcA, 64);
      const uint32 a1e = (uint32)__shfl((int)e1, srcA, 64);
      const uint32 a1o = (uint32)__shfl((int)d1, srcA, 64);
      const uint32 a2e = (uint32)__shfl((int)e0, srcB, 64);
      const uint32 a2o = (uint32)__shfl((int)d0, srcB, 64);
      const uint32 a3e = (uint32)__shfl((int)e1, srcB, 64);
      const uint32 a3o = (uint32)__shfl((int)d1, srcB, 64);
      uint4 pw;
      pw.x = loSel ? a0e : a0o;
      pw.y = loSel ? a1e : a1o;
      pw.z = loSel ? a2e : a2o;
      pw.w = loSel ? a3e : a3o;
      const short8 pf = *reinterpret_cast<const short8*>(&pw);
      const short8 v0 = *reinterpret_cast<const short8*>(&Vt[c16][ks * 32 + q4 * 8]);
      const short8 v1 = *reinterpret_cast<const short8*>(&Vt[16 + c16][ks * 32 + q4 * 8]);
      o0 = __builtin_amdgcn_mfma_f32_16x16x32_bf16(pf, v0, o0, 0, 0, 0);
      o1 = __builtin_amdgcn_mfma_f32_16x16x32_bf16(pf, v1, o1, 0, 0, 0);
    }

    // O epilogue: D[row=q4*4+r -> i][col=c16 -> d]; gather 1/sum from row-owner lanes
    float rsv[4];
#pragma unroll
    for (int r = 0; r < 4; ++r) rsv[r] = __shfl(rinv, q4 * 4 + r, 64);
#pragma unroll
    for (int r = 0; r < 4; ++r) {
      const int i = qt * 16 + q4 * 4 + r;
      if (i < NTOK) {
        const size_t ob = ((size_t)s * TOK + (size_t)b * NTOK + i) * DIMC + h * HDIM;
        op[ob + c16]      = f2bf(o0[r] * rsv[r]);
        op[ob + 16 + c16] = f2bf(o1[r] * rsv[r]);
      }
    }
  }
}

// ---------------- output projection: MFMA bf16, 64-row blocks, 3 col-tiles ----------------
__global__ __launch_bounds__(256) void k_proj(const unsigned short* __restrict__ Oin,
                                              const float* __restrict__ w,
                                              const float* __restrict__ pb,
                                              float* __restrict__ out) {
  __shared__ unsigned short Xs[64][200];
  __shared__ unsigned short Ws[64][200];
  const int R0 = blockIdx.x * 64;
  const int tid = threadIdx.x;
  const int lane = tid & 63, wv = tid >> 6;
  const int c16 = lane & 15, q4 = lane >> 4;
  const int wr = wv >> 1, wc = wv & 1;

  for (int c = tid; c < 64 * 24; c += 256) {
    const int r = c / 24, k8 = (c % 24) * 8;
    *reinterpret_cast<uint4*>(&Xs[r][k8]) =
        *reinterpret_cast<const uint4*>(&Oin[(size_t)(R0 + r) * DIMC + k8]);
  }

  for (int ct = 0; ct < 3; ++ct) {
    __syncthreads();
    for (int c = tid; c < 64 * 24; c += 256) {
      const int r = c / 24, k8 = (c % 24) * 8;
      const float* p = &w[(size_t)(ct * 64 + r) * DIMC + k8];
      const float4 a = *reinterpret_cast<const float4*>(p);
      const float4 b = *reinterpret_cast<const float4*>(p + 4);
      *reinterpret_cast<uint4*>(&Ws[r][k8]) = pack8bf(a, b);
    }
    __syncthreads();

    const int colbase = ct * 64 + wc * 32;
    f32x4 acc[2][2];
#pragma unroll
    for (int n = 0; n < 2; ++n) {
      const float bv = pb[colbase + n * 16 + c16];
      acc[0][n] = f32x4{bv, bv, bv, bv};
      acc[1][n] = f32x4{bv, bv, bv, bv};
    }
#pragma unroll
    for (int ks = 0; ks < 6; ++ks) {
      const short8 a0 = *reinterpret_cast<const short8*>(&Xs[wr * 32 + c16][ks * 32 + q4 * 8]);
      const short8 a1 = *reinterpret_cast<const short8*>(&Xs[wr * 32 + 16 + c16][ks * 32 + q4 * 8]);
      const short8 b0 = *reinterpret_cast<const short8*>(&Ws[wc * 32 + c16][ks * 32 + q4 * 8]);
      const short8 b1 = *reinterpret_cast<const short8*>(&Ws[wc * 32 + 16 + c16][ks * 32 + q4 * 8]);
      acc[0][0] = __builtin_amdgcn_mfma_f32_16x16x32_bf16(a0, b0, acc[0][0], 0, 0, 0);
      acc[0][1] = __builtin_amdgcn_mfma_f32_16x16x32_bf16(a0, b1, acc[0][1], 0, 0, 0);
      acc[1][0] = __builtin_amdgcn_mfma_f32_16x16x32_bf16(a1, b0, acc[1][0], 0, 0, 0);
      acc[1][1] = __builtin_amdgcn_mfma_f32_16x16x32_bf16(a1, b1, acc[1][1], 0, 0, 0);
    }

#pragma unroll
    for (int m = 0; m < 2; ++m) {
#pragma unroll
      for (int n = 0; n < 2; ++n) {
        const int col = colbase + n * 16 + c16;
#pragma unroll
        for (int r = 0; r < 4; ++r) {
          const int row = R0 + wr * 32 + m * 16 + q4 * 4 + r;
          out[(size_t)row * DIMC + col] = acc[m][n][r];
        }
      }
    }
  }
}

extern "C" void kernel_launch(void* const* d_in, const int* in_sizes, int n_in,
                              void* d_out, int out_size, void* d_ws, size_t ws_size,
                              hipStream_t stream) {
  const float* x      = (const float*)d_in[0];
  const float* x1     = (const float*)d_in[1];
  const float* qkv_w  = (const float*)d_in[2];
  const float* qkv_b  = (const float*)d_in[3];
  const float* proj_w = (const float*)d_in[4];
  const float* proj_b = (const float*)d_in[5];
  const float* rpb    = (const float*)d_in[6];
  const int*   ridx   = (const int*)d_in[7];
  float* out = (float*)d_out;

  // workspace: qkv bf16 101,154,816 B | O bf16 33,718,272 B | bias f32 (stride 344) 2,831,808 B
  char* ws = (char*)d_ws;
  unsigned short* qkv  = (unsigned short*)ws;
  unsigned short* Ows  = (unsigned short*)(ws + 101154816);
  float*          bws  = (float*)(ws + 101154816 + 33718272);

  k_bias<<<(NN + 255) / 256, 256, 0, stream>>>(rpb, ridx, bws);
  k_qkv<<<M2 / 64, 256, 0, stream>>>(x, x1, qkv_w, qkv_b, qkv);
  k_attn<<<2 * BW * NHEAD, 256, 0, stream>>>((const __hip_bfloat16*)qkv, bws,
                                             (__hip_bfloat16*)Ows);
  k_proj<<<M2 / 64, 256, 0, stream>>>(Ows, proj_w, proj_b, out);
}

// Round 9
// 241.591 us; speedup vs baseline: 15.4545x; 1.1139x over previous
//
#include <hip/hip_runtime.h>
#include <hip/hip_bf16.h>

#define BW 128
#define NTOK 343
#define DIMC 192
#define NHEAD 6
#define HDIM 32
#define TOK (BW * NTOK)      // 43904
#define M2 (2 * TOK)         // 87808
#define NN (NTOK * NTOK)     // 117649
#define BSTR 344             // padded bias row stride (16B-aligned float4 reads)
#define BNN (NTOK * BSTR)    // 117992 per head
#define QSCALE 0.17677669529663687f
#define LOG2E 1.4426950408889634f

typedef unsigned int uint32;
typedef __attribute__((ext_vector_type(8))) short short8;   // 8 bf16 = 4 VGPR
typedef __attribute__((ext_vector_type(4))) float f32x4;

// round-to-nearest-even f32 -> bf16 bits
__device__ __forceinline__ unsigned short f2bf(float f) {
  uint32 u = __float_as_uint(f);
  u += 0x7fffu + ((u >> 16) & 1u);
  return (unsigned short)(u >> 16);
}

__device__ __forceinline__ uint32 pkpair(float a, float b) {
  return (uint32)f2bf(a) | ((uint32)f2bf(b) << 16);
}

__device__ __forceinline__ uint4 pack8bf(const float4 a, const float4 b) {
  uint4 pk;
  pk.x = pkpair(a.x, a.y);
  pk.y = pkpair(a.z, a.w);
  pk.z = pkpair(b.x, b.y);
  pk.w = pkpair(b.z, b.w);
  return pk;
}

// native 2^x (v_exp_f32); logits carry log2e factor so this IS softmax's exp
__device__ __forceinline__ float fexp2(float x) {
  float r;
  asm("v_exp_f32 %0, %1" : "=v"(r) : "v"(x));
  return r;
}

// ---------------- bias gather: bias[h][i][j] = rpb[rel_idx[i,j]*NH + h] * log2e ----------------
__global__ void k_bias(const float* __restrict__ rpb, const int* __restrict__ ridx,
                       float* __restrict__ biasws) {
  const int idx = blockIdx.x * 256 + threadIdx.x;
  if (idx < NN) {
    const int r = ridx[idx];
    const int i = idx / NTOK, j = idx % NTOK;
#pragma unroll
    for (int h = 0; h < NHEAD; ++h)
      biasws[h * BNN + i * BSTR + j] = rpb[r * NHEAD + h] * LOG2E;
  }
}

// ---------------- QKV projection: MFMA bf16, 64-row blocks, 9 col-tiles looped ----------------
__global__ __launch_bounds__(256) void k_qkv(const float* __restrict__ x,
                                             const float* __restrict__ x1,
                                             const float* __restrict__ w,
                                             const float* __restrict__ bvec,
                                             unsigned short* __restrict__ qkvo) {
  __shared__ unsigned short Xs[64][200];
  __shared__ unsigned short Ws[64][200];
  const int R0 = blockIdx.x * 64;
  const int s = R0 / TOK;
  const int tokbase = R0 % TOK;
  const float* __restrict__ src = s ? x1 : x;
  const int tid = threadIdx.x;
  const int lane = tid & 63, wv = tid >> 6;
  const int c16 = lane & 15, q4 = lane >> 4;
  const int wr = wv >> 1, wc = wv & 1;

  for (int c = tid; c < 64 * 24; c += 256) {
    const int r = c / 24, k8 = (c % 24) * 8;
    const float* p = &src[(size_t)(tokbase + r) * DIMC + k8];
    const float4 a = *reinterpret_cast<const float4*>(p);
    const float4 b = *reinterpret_cast<const float4*>(p + 4);
    *reinterpret_cast<uint4*>(&Xs[r][k8]) = pack8bf(a, b);
  }

  for (int ct = 0; ct < 9; ++ct) {
    __syncthreads();
    for (int c = tid; c < 64 * 24; c += 256) {
      const int r = c / 24, k8 = (c % 24) * 8;
      const float* p = &w[(size_t)(ct * 64 + r) * DIMC + k8];
      const float4 a = *reinterpret_cast<const float4*>(p);
      const float4 b = *reinterpret_cast<const float4*>(p + 4);
      *reinterpret_cast<uint4*>(&Ws[r][k8]) = pack8bf(a, b);
    }
    __syncthreads();

    const int colbase = ct * 64 + wc * 32;
    f32x4 acc[2][2];
#pragma unroll
    for (int n = 0; n < 2; ++n) {
      const float bv = bvec[colbase + n * 16 + c16];
      acc[0][n] = f32x4{bv, bv, bv, bv};
      acc[1][n] = f32x4{bv, bv, bv, bv};
    }
#pragma unroll
    for (int ks = 0; ks < 6; ++ks) {
      const short8 a0 = *reinterpret_cast<const short8*>(&Xs[wr * 32 + c16][ks * 32 + q4 * 8]);
      const short8 a1 = *reinterpret_cast<const short8*>(&Xs[wr * 32 + 16 + c16][ks * 32 + q4 * 8]);
      const short8 b0 = *reinterpret_cast<const short8*>(&Ws[wc * 32 + c16][ks * 32 + q4 * 8]);
      const short8 b1 = *reinterpret_cast<const short8*>(&Ws[wc * 32 + 16 + c16][ks * 32 + q4 * 8]);
      acc[0][0] = __builtin_amdgcn_mfma_f32_16x16x32_bf16(a0, b0, acc[0][0], 0, 0, 0);
      acc[0][1] = __builtin_amdgcn_mfma_f32_16x16x32_bf16(a0, b1, acc[0][1], 0, 0, 0);
      acc[1][0] = __builtin_amdgcn_mfma_f32_16x16x32_bf16(a1, b0, acc[1][0], 0, 0, 0);
      acc[1][1] = __builtin_amdgcn_mfma_f32_16x16x32_bf16(a1, b1, acc[1][1], 0, 0, 0);
    }

#pragma unroll
    for (int n = 0; n < 2; ++n) {
      const int col = colbase + n * 16 + c16;
      const int t = col / DIMC;
      const int h = (col % DIMC) / HDIM;
      const int d = col % HDIM;
      // Q carries softmax scale AND log2e (softmax via native 2^x in k_attn)
      const float qs = (t == 0) ? (QSCALE * LOG2E) : 1.0f;
#pragma unroll
      for (int m = 0; m < 2; ++m) {
#pragma unroll
        for (int r = 0; r < 4; ++r) {
          const int token = tokbase + wr * 32 + m * 16 + q4 * 4 + r;
          const int bidx = token / NTOK;
          const int nn = token % NTOK;
          const size_t ob =
              ((((size_t)(s * 3 + t) * BW + bidx) * NHEAD + h) * NTOK + nn) * HDIM + d;
          qkvo[ob] = f2bf(acc[m][n][r] * qs);
        }
      }
    }
  }
}

// ---------------- MFMA attention, swapped QK^T + k-permuted PV (zero-shuffle) ----------------
// S^T via mfma(K,Q): lane(c16,q4) holds S[i=qt*16+c16][j=kt*16+q4*4+r] in acc[kt][r].
// PV uses k-permutation pi(q4,e): dot products are k-order invariant, so permuting
// the physical j assigned to each MFMA k-slot is legal if A and B frags agree.
// pi puts P's A-frag entirely in the lane's own registers (4 pkpair, no shuffles);
// V B-frag becomes two 8B reads per operand.
__global__ __launch_bounds__(256) void k_attn(const __hip_bfloat16* __restrict__ qkvi,
                                              const float* __restrict__ biasws,
                                              __hip_bfloat16* __restrict__ Ows) {
  __shared__ unsigned short Ks[352][40];      // 28160 B
  __shared__ unsigned short Vt[32][360];      // 23040 B, V transposed [d][n]
  const int bid = blockIdx.x;
  const int h = bid / (2 * BW);
  const int sb = bid % (2 * BW);
  const int s = sb >> 7;
  const int b = sb & 127;
  const int so = 1 - s;
  const size_t qbase = (((size_t)(s * 3 + 0) * BW + b) * NHEAD + h) * (size_t)NTOK * HDIM;
  const size_t kbase = (((size_t)(so * 3 + 1) * BW + b) * NHEAD + h) * (size_t)NTOK * HDIM;
  const size_t vbase = (((size_t)(so * 3 + 2) * BW + b) * NHEAD + h) * (size_t)NTOK * HDIM;
  const unsigned short* __restrict__ qp = (const unsigned short*)qkvi;
  unsigned short* __restrict__ op = (unsigned short*)Ows;
  const float* __restrict__ bh = biasws + (size_t)h * BNN;
  const int tid = threadIdx.x;

  for (int idx = tid; idx < 352 * 4; idx += 256) {
    const int n = idx >> 2, d0 = (idx & 3) * 8;
    uint4 v = {0u, 0u, 0u, 0u};
    if (n < NTOK) v = *reinterpret_cast<const uint4*>(qp + kbase + (size_t)n * HDIM + d0);
    *reinterpret_cast<uint4*>(&Ks[n][d0]) = v;
  }
  for (int idx = tid; idx < NTOK * 4; idx += 256) {
    const int n = idx >> 2, d0 = (idx & 3) * 8;
    const uint4 v = *reinterpret_cast<const uint4*>(qp + vbase + (size_t)n * HDIM + d0);
    const unsigned short* ep = reinterpret_cast<const unsigned short*>(&v);
#pragma unroll
    for (int e = 0; e < 8; ++e) Vt[d0 + e][n] = ep[e];
  }
  for (int idx = tid; idx < 32 * 9; idx += 256) Vt[idx / 9][NTOK + idx % 9] = 0;
  __syncthreads();

  const int lane = tid & 63, w = tid >> 6;
  const int c16 = lane & 15, q4 = lane >> 4;
  const bool loSel = (q4 < 2);   // kt=21 bias-load clamp (stay inside row stride)

  for (int qt = w; qt < 22; qt += 4) {
    const int iq = qt * 16 + c16;                     // this lane's softmax row
    const int iqc = (iq < NTOK) ? iq : NTOK - 1;      // clamp (dup rows masked by O-write)
    const short8 qf = *reinterpret_cast<const short8*>(qp + qbase + (size_t)iqc * HDIM + q4 * 8);

    // C-init = bias[iqc][kt*16 + q4*4 ..+3] (aligned float4; kt=21 clamped, masked below)
    f32x4 acc[22];
    const float* brow = bh + (size_t)iqc * BSTR;
#pragma unroll
    for (int kt = 0; kt < 22; ++kt) {
      const int jb = (kt < 21) ? (kt * 16 + q4 * 4) : (336 + (loSel ? q4 * 4 : 0));
      const float4 bv = *reinterpret_cast<const float4*>(brow + jb);
      acc[kt] = f32x4{bv.x, bv.y, bv.z, bv.w};
    }
    // swapped QK^T: 22 MFMAs
#pragma unroll
    for (int kt = 0; kt < 22; ++kt) {
      const short8 kf = *reinterpret_cast<const short8*>(&Ks[kt * 16 + c16][q4 * 8]);
      acc[kt] = __builtin_amdgcn_mfma_f32_16x16x32_bf16(kf, qf, acc[kt], 0, 0, 0);
    }
    // mask invalid j: kt=21, j = 336 + q4*4 + r >= 343
#pragma unroll
    for (int r = 0; r < 4; ++r)
      if (q4 * 4 + r >= 7) acc[21][r] = -1e30f;

    // row softmax fully in-register (logits carry log2e -> native 2^x)
    float m = acc[0][0];
#pragma unroll
    for (int kt = 0; kt < 22; ++kt)
#pragma unroll
      for (int r = 0; r < 4; ++r) m = fmaxf(m, acc[kt][r]);
    m = fmaxf(m, __shfl_xor(m, 16, 64));
    m = fmaxf(m, __shfl_xor(m, 32, 64));
    float sum = 0.f;
#pragma unroll
    for (int kt = 0; kt < 22; ++kt)
#pragma unroll
      for (int r = 0; r < 4; ++r) {
        const float p = fexp2(acc[kt][r] - m);
        acc[kt][r] = p;
        sum += p;
      }
    sum += __shfl_xor(sum, 16, 64);
    sum += __shfl_xor(sum, 32, 64);
    const float rinv = 1.f / sum;

    // PV with k-permutation pi(q4,e) = 32ks + 4q4 + e (e<4) | 32ks+16+4q4+e-4 (e>=4):
    // A-frag = own registers {acc[2ks][0..3], acc[2ks+1][0..3]} -> 4 pkpair, 0 shuffles.
    // B-frag: element e -> Vt[d][pi(q4,e)] -> two 8B reads per operand row.
    f32x4 o0 = {0.f, 0.f, 0.f, 0.f}, o1 = {0.f, 0.f, 0.f, 0.f};
#pragma unroll
    for (int ks = 0; ks < 11; ++ks) {
      uint4 pw;
      pw.x = pkpair(acc[2 * ks][0], acc[2 * ks][1]);
      pw.y = pkpair(acc[2 * ks][2], acc[2 * ks][3]);
      pw.z = pkpair(acc[2 * ks + 1][0], acc[2 * ks + 1][1]);
      pw.w = pkpair(acc[2 * ks + 1][2], acc[2 * ks + 1][3]);
      const short8 pf = *reinterpret_cast<const short8*>(&pw);

      const uint2 v0lo = *reinterpret_cast<const uint2*>(&Vt[c16][ks * 32 + q4 * 4]);
      const uint2 v0hi = *reinterpret_cast<const uint2*>(&Vt[c16][ks * 32 + 16 + q4 * 4]);
      const uint2 v1lo = *reinterpret_cast<const uint2*>(&Vt[16 + c16][ks * 32 + q4 * 4]);
      const uint2 v1hi = *reinterpret_cast<const uint2*>(&Vt[16 + c16][ks * 32 + 16 + q4 * 4]);
      uint4 vw0, vw1;
      vw0.x = v0lo.x; vw0.y = v0lo.y; vw0.z = v0hi.x; vw0.w = v0hi.y;
      vw1.x = v1lo.x; vw1.y = v1lo.y; vw1.z = v1hi.x; vw1.w = v1hi.y;
      const short8 v0 = *reinterpret_cast<const short8*>(&vw0);
      const short8 v1 = *reinterpret_cast<const short8*>(&vw1);

      o0 = __builtin_amdgcn_mfma_f32_16x16x32_bf16(pf, v0, o0, 0, 0, 0);
      o1 = __builtin_amdgcn_mfma_f32_16x16x32_bf16(pf, v1, o1, 0, 0, 0);
    }

    // O epilogue: D[row=q4*4+r -> i][col=c16 -> d]; gather 1/sum from row-owner lanes
    float rsv[4];
#pragma unroll
    for (int r = 0; r < 4; ++r) rsv[r] = __shfl(rinv, q4 * 4 + r, 64);
#pragma unroll
    for (int r = 0; r < 4; ++r) {
      const int i = qt * 16 + q4 * 4 + r;
      if (i < NTOK) {
        const size_t ob = ((size_t)s * TOK + (size_t)b * NTOK + i) * DIMC + h * HDIM;
        op[ob + c16]      = f2bf(o0[r] * rsv[r]);
        op[ob + 16 + c16] = f2bf(o1[r] * rsv[r]);
      }
    }
  }
}

// ---------------- output projection: MFMA bf16, 64-row blocks, 3 col-tiles ----------------
__global__ __launch_bounds__(256) void k_proj(const unsigned short* __restrict__ Oin,
                                              const float* __restrict__ w,
                                              const float* __restrict__ pb,
                                              float* __restrict__ out) {
  __shared__ unsigned short Xs[64][200];
  __shared__ unsigned short Ws[64][200];
  const int R0 = blockIdx.x * 64;
  const int tid = threadIdx.x;
  const int lane = tid & 63, wv = tid >> 6;
  const int c16 = lane & 15, q4 = lane >> 4;
  const int wr = wv >> 1, wc = wv & 1;

  for (int c = tid; c < 64 * 24; c += 256) {
    const int r = c / 24, k8 = (c % 24) * 8;
    *reinterpret_cast<uint4*>(&Xs[r][k8]) =
        *reinterpret_cast<const uint4*>(&Oin[(size_t)(R0 + r) * DIMC + k8]);
  }

  for (int ct = 0; ct < 3; ++ct) {
    __syncthreads();
    for (int c = tid; c < 64 * 24; c += 256) {
      const int r = c / 24, k8 = (c % 24) * 8;
      const float* p = &w[(size_t)(ct * 64 + r) * DIMC + k8];
      const float4 a = *reinterpret_cast<const float4*>(p);
      const float4 b = *reinterpret_cast<const float4*>(p + 4);
      *reinterpret_cast<uint4*>(&Ws[r][k8]) = pack8bf(a, b);
    }
    __syncthreads();

    const int colbase = ct * 64 + wc * 32;
    f32x4 acc[2][2];
#pragma unroll
    for (int n = 0; n < 2; ++n) {
      const float bv = pb[colbase + n * 16 + c16];
      acc[0][n] = f32x4{bv, bv, bv, bv};
      acc[1][n] = f32x4{bv, bv, bv, bv};
    }
#pragma unroll
    for (int ks = 0; ks < 6; ++ks) {
      const short8 a0 = *reinterpret_cast<const short8*>(&Xs[wr * 32 + c16][ks * 32 + q4 * 8]);
      const short8 a1 = *reinterpret_cast<const short8*>(&Xs[wr * 32 + 16 + c16][ks * 32 + q4 * 8]);
      const short8 b0 = *reinterpret_cast<const short8*>(&Ws[wc * 32 + c16][ks * 32 + q4 * 8]);
      const short8 b1 = *reinterpret_cast<const short8*>(&Ws[wc * 32 + 16 + c16][ks * 32 + q4 * 8]);
      acc[0][0] = __builtin_amdgcn_mfma_f32_16x16x32_bf16(a0, b0, acc[0][0], 0, 0, 0);
      acc[0][1] = __builtin_amdgcn_mfma_f32_16x16x32_bf16(a0, b1, acc[0][1], 0, 0, 0);
      acc[1][0] = __builtin_amdgcn_mfma_f32_16x16x32_bf16(a1, b0, acc[1][0], 0, 0, 0);
      acc[1][1] = __builtin_amdgcn_mfma_f32_16x16x32_bf16(a1, b1, acc[1][1], 0, 0, 0);
    }

#pragma unroll
    for (int m = 0; m < 2; ++m) {
#pragma unroll
      for (int n = 0; n < 2; ++n) {
        const int col = colbase + n * 16 + c16;
#pragma unroll
        for (int r = 0; r < 4; ++r) {
          const int row = R0 + wr * 32 + m * 16 + q4 * 4 + r;
          out[(size_t)row * DIMC + col] = acc[m][n][r];
        }
      }
    }
  }
}

extern "C" void kernel_launch(void* const* d_in, const int* in_sizes, int n_in,
                              void* d_out, int out_size, void* d_ws, size_t ws_size,
                              hipStream_t stream) {
  const float* x      = (const float*)d_in[0];
  const float* x1     = (const float*)d_in[1];
  const float* qkv_w  = (const float*)d_in[2];
  const float* qkv_b  = (const float*)d_in[3];
  const float* proj_w = (const float*)d_in[4];
  const float* proj_b = (const float*)d_in[5];
  const float* rpb    = (const float*)d_in[6];
  const int*   ridx   = (const int*)d_in[7];
  float* out = (float*)d_out;

  // workspace: qkv bf16 101,154,816 B | O bf16 33,718,272 B | bias f32 (stride 344) 2,831,808 B
  char* ws = (char*)d_ws;
  unsigned short* qkv  = (unsigned short*)ws;
  unsigned short* Ows  = (unsigned short*)(ws + 101154816);
  float*          bws  = (float*)(ws + 101154816 + 33718272);

  k_bias<<<(NN + 255) / 256, 256, 0, stream>>>(rpb, ridx, bws);
  k_qkv<<<M2 / 64, 256, 0, stream>>>(x, x1, qkv_w, qkv_b, qkv);
  k_attn<<<2 * BW * NHEAD, 256, 0, stream>>>((const __hip_bfloat16*)qkv, bws,
                                             (__hip_bfloat16*)Ows);
  k_proj<<<M2 / 64, 256, 0, stream>>>(Ows, proj_w, proj_b, out);
}

// Round 10
// 191.721 us; speedup vs baseline: 19.4745x; 1.2601x over previous
//
#include <hip/hip_runtime.h>
#include <hip/hip_bf16.h>

#define BW 128
#define NTOK 343
#define DIMC 192
#define NHEAD 6
#define HDIM 32
#define TOK (BW * NTOK)      // 43904
#define M2 (2 * TOK)         // 87808
#define NN (NTOK * NTOK)     // 117649
#define BSTR 344             // padded bias row stride (16B-aligned float4 reads)
#define BNN (NTOK * BSTR)    // 117992 per head
#define QSCALE 0.17677669529663687f
#define LOG2E 1.4426950408889634f

typedef unsigned int uint32;
typedef __attribute__((ext_vector_type(8))) short short8;   // 8 bf16 = 4 VGPR
typedef __attribute__((ext_vector_type(4))) float f32x4;

// round-to-nearest-even f32 -> bf16 bits (scalar path)
__device__ __forceinline__ unsigned short f2bf(float f) {
  uint32 u = __float_as_uint(f);
  u += 0x7fffu + ((u >> 16) & 1u);
  return (unsigned short)(u >> 16);
}

// pair pack via v_cvt_pk_bf16_f32 (semantic form; m240: casts beat hand bit-ops)
__device__ __forceinline__ uint32 pkpair(float a, float b) {
  __hip_bfloat162 h = __float22bfloat162_rn(make_float2(a, b));
  uint32 u;
  __builtin_memcpy(&u, &h, 4);
  return u;
}

__device__ __forceinline__ uint4 pack8bf(const float4 a, const float4 b) {
  uint4 pk;
  pk.x = pkpair(a.x, a.y);
  pk.y = pkpair(a.z, a.w);
  pk.z = pkpair(b.x, b.y);
  pk.w = pkpair(b.z, b.w);
  return pk;
}

// native 2^x (v_exp_f32); logits carry log2e factor so this IS softmax's exp
__device__ __forceinline__ float fexp2(float x) {
  float r;
  asm("v_exp_f32 %0, %1" : "=v"(r) : "v"(x));
  return r;
}

// ---------------- bias gather: bias[h][i][j] = rpb[rel_idx[i,j]*NH + h] * log2e ----------------
__global__ void k_bias(const float* __restrict__ rpb, const int* __restrict__ ridx,
                       float* __restrict__ biasws) {
  const int idx = blockIdx.x * 256 + threadIdx.x;
  if (idx < NN) {
    const int r = ridx[idx];
    const int i = idx / NTOK, j = idx % NTOK;
#pragma unroll
    for (int h = 0; h < NHEAD; ++h)
      biasws[h * BNN + i * BSTR + j] = rpb[r * NHEAD + h] * LOG2E;
  }
}

// ---------------- QKV projection: MFMA bf16, 64-row blocks, 9 col-tiles looped ----------------
__global__ __launch_bounds__(256) void k_qkv(const float* __restrict__ x,
                                             const float* __restrict__ x1,
                                             const float* __restrict__ w,
                                             const float* __restrict__ bvec,
                                             unsigned short* __restrict__ qkvo) {
  __shared__ unsigned short Xs[64][200];
  __shared__ unsigned short Ws[64][200];
  const int R0 = blockIdx.x * 64;
  const int s = R0 / TOK;
  const int tokbase = R0 % TOK;
  const float* __restrict__ src = s ? x1 : x;
  const int tid = threadIdx.x;
  const int lane = tid & 63, wv = tid >> 6;
  const int c16 = lane & 15, q4 = lane >> 4;
  const int wr = wv >> 1, wc = wv & 1;

  for (int c = tid; c < 64 * 24; c += 256) {
    const int r = c / 24, k8 = (c % 24) * 8;
    const float* p = &src[(size_t)(tokbase + r) * DIMC + k8];
    const float4 a = *reinterpret_cast<const float4*>(p);
    const float4 b = *reinterpret_cast<const float4*>(p + 4);
    *reinterpret_cast<uint4*>(&Xs[r][k8]) = pack8bf(a, b);
  }

  for (int ct = 0; ct < 9; ++ct) {
    __syncthreads();
    for (int c = tid; c < 64 * 24; c += 256) {
      const int r = c / 24, k8 = (c % 24) * 8;
      const float* p = &w[(size_t)(ct * 64 + r) * DIMC + k8];
      const float4 a = *reinterpret_cast<const float4*>(p);
      const float4 b = *reinterpret_cast<const float4*>(p + 4);
      *reinterpret_cast<uint4*>(&Ws[r][k8]) = pack8bf(a, b);
    }
    __syncthreads();

    const int colbase = ct * 64 + wc * 32;
    f32x4 acc[2][2];
#pragma unroll
    for (int n = 0; n < 2; ++n) {
      const float bv = bvec[colbase + n * 16 + c16];
      acc[0][n] = f32x4{bv, bv, bv, bv};
      acc[1][n] = f32x4{bv, bv, bv, bv};
    }
#pragma unroll
    for (int ks = 0; ks < 6; ++ks) {
      const short8 a0 = *reinterpret_cast<const short8*>(&Xs[wr * 32 + c16][ks * 32 + q4 * 8]);
      const short8 a1 = *reinterpret_cast<const short8*>(&Xs[wr * 32 + 16 + c16][ks * 32 + q4 * 8]);
      const short8 b0 = *reinterpret_cast<const short8*>(&Ws[wc * 32 + c16][ks * 32 + q4 * 8]);
      const short8 b1 = *reinterpret_cast<const short8*>(&Ws[wc * 32 + 16 + c16][ks * 32 + q4 * 8]);
      acc[0][0] = __builtin_amdgcn_mfma_f32_16x16x32_bf16(a0, b0, acc[0][0], 0, 0, 0);
      acc[0][1] = __builtin_amdgcn_mfma_f32_16x16x32_bf16(a0, b1, acc[0][1], 0, 0, 0);
      acc[1][0] = __builtin_amdgcn_mfma_f32_16x16x32_bf16(a1, b0, acc[1][0], 0, 0, 0);
      acc[1][1] = __builtin_amdgcn_mfma_f32_16x16x32_bf16(a1, b1, acc[1][1], 0, 0, 0);
    }

#pragma unroll
    for (int n = 0; n < 2; ++n) {
      const int col = colbase + n * 16 + c16;
      const int t = col / DIMC;
      const int h = (col % DIMC) / HDIM;
      const int d = col % HDIM;
      // Q carries softmax scale AND log2e (softmax via native 2^x in k_attn)
      const float qs = (t == 0) ? (QSCALE * LOG2E) : 1.0f;
#pragma unroll
      for (int m = 0; m < 2; ++m) {
#pragma unroll
        for (int r = 0; r < 4; ++r) {
          const int token = tokbase + wr * 32 + m * 16 + q4 * 4 + r;
          const int bidx = token / NTOK;
          const int nn = token % NTOK;
          const size_t ob =
              ((((size_t)(s * 3 + t) * BW + bidx) * NHEAD + h) * NTOK + nn) * HDIM + d;
          qkvo[ob] = f2bf(acc[m][n][r] * qs);
        }
      }
    }
  }
}

// ---------------- MFMA attention: swapped QK^T + zero-shuffle PV + split-K online softmax ----------------
// Phase A: kt 0..11 (j 0..191): S-A, softmax-A (mA), PV-A (ks 0..5) -> frees 48-reg acc.
// Phase B: kt 12..21 (j 192..351): S-B, final m, rescale o by alpha=2^(mA-m), PV-B (ks 6..10).
// Register peak ~phaseA(48 acc + o + frags) -> target <=128 VGPR for 3+ waves/SIMD.
__global__ __launch_bounds__(256) void k_attn(const __hip_bfloat16* __restrict__ qkvi,
                                              const float* __restrict__ biasws,
                                              __hip_bfloat16* __restrict__ Ows) {
  __shared__ unsigned short Ks[352][40];      // 28160 B
  __shared__ unsigned short Vt[32][360];      // 23040 B, V transposed [d][n]
  const int bid = blockIdx.x;
  const int h = bid / (2 * BW);
  const int sb = bid % (2 * BW);
  const int s = sb >> 7;
  const int b = sb & 127;
  const int so = 1 - s;
  const size_t qbase = (((size_t)(s * 3 + 0) * BW + b) * NHEAD + h) * (size_t)NTOK * HDIM;
  const size_t kbase = (((size_t)(so * 3 + 1) * BW + b) * NHEAD + h) * (size_t)NTOK * HDIM;
  const size_t vbase = (((size_t)(so * 3 + 2) * BW + b) * NHEAD + h) * (size_t)NTOK * HDIM;
  const unsigned short* __restrict__ qp = (const unsigned short*)qkvi;
  unsigned short* __restrict__ op = (unsigned short*)Ows;
  const float* __restrict__ bh = biasws + (size_t)h * BNN;
  const int tid = threadIdx.x;

  for (int idx = tid; idx < 352 * 4; idx += 256) {
    const int n = idx >> 2, d0 = (idx & 3) * 8;
    uint4 v = {0u, 0u, 0u, 0u};
    if (n < NTOK) v = *reinterpret_cast<const uint4*>(qp + kbase + (size_t)n * HDIM + d0);
    *reinterpret_cast<uint4*>(&Ks[n][d0]) = v;
  }
  for (int idx = tid; idx < NTOK * 4; idx += 256) {
    const int n = idx >> 2, d0 = (idx & 3) * 8;
    const uint4 v = *reinterpret_cast<const uint4*>(qp + vbase + (size_t)n * HDIM + d0);
    const unsigned short* ep = reinterpret_cast<const unsigned short*>(&v);
#pragma unroll
    for (int e = 0; e < 8; ++e) Vt[d0 + e][n] = ep[e];
  }
  for (int idx = tid; idx < 32 * 9; idx += 256) Vt[idx / 9][NTOK + idx % 9] = 0;
  __syncthreads();

  const int lane = tid & 63, w = tid >> 6;
  const int c16 = lane & 15, q4 = lane >> 4;
  const bool loSel = (q4 < 2);   // kt=21 bias-load clamp (stay inside row stride)

  for (int qt = w; qt < 22; qt += 4) {
    const int iq = qt * 16 + c16;                     // this lane's softmax row
    const int iqc = (iq < NTOK) ? iq : NTOK - 1;      // clamp (dup rows masked by O-write)
    const short8 qf = *reinterpret_cast<const short8*>(qp + qbase + (size_t)iqc * HDIM + q4 * 8);
    const float* brow = bh + (size_t)iqc * BSTR;

    f32x4 o0 = {0.f, 0.f, 0.f, 0.f}, o1 = {0.f, 0.f, 0.f, 0.f};
    float mA, sumA;   // phase-A row max (cross-lane), per-lane partial sum

    // ================= Phase A: kt 0..11 =================
    {
      f32x4 acc[12];
#pragma unroll
      for (int kt = 0; kt < 12; ++kt) {
        const float4 bv = *reinterpret_cast<const float4*>(brow + kt * 16 + q4 * 4);
        acc[kt] = f32x4{bv.x, bv.y, bv.z, bv.w};
      }
#pragma unroll
      for (int kt = 0; kt < 12; ++kt) {
        const short8 kf = *reinterpret_cast<const short8*>(&Ks[kt * 16 + c16][q4 * 8]);
        acc[kt] = __builtin_amdgcn_mfma_f32_16x16x32_bf16(kf, qf, acc[kt], 0, 0, 0);
      }
      float m = acc[0][0];
#pragma unroll
      for (int kt = 0; kt < 12; ++kt)
#pragma unroll
        for (int r = 0; r < 4; ++r) m = fmaxf(m, acc[kt][r]);
      m = fmaxf(m, __shfl_xor(m, 16, 64));
      m = fmaxf(m, __shfl_xor(m, 32, 64));
      mA = m;
      float sum = 0.f;
#pragma unroll
      for (int kt = 0; kt < 12; ++kt)
#pragma unroll
        for (int r = 0; r < 4; ++r) {
          const float p = fexp2(acc[kt][r] - m);
          acc[kt][r] = p;
          sum += p;
        }
      sumA = sum;   // per-lane partial; cross-lane reduce deferred to phase B

      // PV-A: ks 0..5 (j 0..191)
#pragma unroll
      for (int ks = 0; ks < 6; ++ks) {
        uint4 pw;
        pw.x = pkpair(acc[2 * ks][0], acc[2 * ks][1]);
        pw.y = pkpair(acc[2 * ks][2], acc[2 * ks][3]);
        pw.z = pkpair(acc[2 * ks + 1][0], acc[2 * ks + 1][1]);
        pw.w = pkpair(acc[2 * ks + 1][2], acc[2 * ks + 1][3]);
        const short8 pf = *reinterpret_cast<const short8*>(&pw);
        const uint2 v0lo = *reinterpret_cast<const uint2*>(&Vt[c16][ks * 32 + q4 * 4]);
        const uint2 v0hi = *reinterpret_cast<const uint2*>(&Vt[c16][ks * 32 + 16 + q4 * 4]);
        const uint2 v1lo = *reinterpret_cast<const uint2*>(&Vt[16 + c16][ks * 32 + q4 * 4]);
        const uint2 v1hi = *reinterpret_cast<const uint2*>(&Vt[16 + c16][ks * 32 + 16 + q4 * 4]);
        uint4 vw0, vw1;
        vw0.x = v0lo.x; vw0.y = v0lo.y; vw0.z = v0hi.x; vw0.w = v0hi.y;
        vw1.x = v1lo.x; vw1.y = v1lo.y; vw1.z = v1hi.x; vw1.w = v1hi.y;
        const short8 v0 = *reinterpret_cast<const short8*>(&vw0);
        const short8 v1 = *reinterpret_cast<const short8*>(&vw1);
        o0 = __builtin_amdgcn_mfma_f32_16x16x32_bf16(pf, v0, o0, 0, 0, 0);
        o1 = __builtin_amdgcn_mfma_f32_16x16x32_bf16(pf, v1, o1, 0, 0, 0);
      }
    }

    // ================= Phase B: kt 12..21 =================
    float rinv;
    {
      f32x4 acc[10];
#pragma unroll
      for (int k2 = 0; k2 < 10; ++k2) {
        const int kt = 12 + k2;
        const int jb = (kt < 21) ? (kt * 16 + q4 * 4) : (336 + (loSel ? q4 * 4 : 0));
        const float4 bv = *reinterpret_cast<const float4*>(brow + jb);
        acc[k2] = f32x4{bv.x, bv.y, bv.z, bv.w};
      }
#pragma unroll
      for (int k2 = 0; k2 < 10; ++k2) {
        const short8 kf = *reinterpret_cast<const short8*>(&Ks[(12 + k2) * 16 + c16][q4 * 8]);
        acc[k2] = __builtin_amdgcn_mfma_f32_16x16x32_bf16(kf, qf, acc[k2], 0, 0, 0);
      }
      // mask invalid j: kt=21 -> j = 336 + q4*4 + r >= 343
#pragma unroll
      for (int r = 0; r < 4; ++r)
        if (q4 * 4 + r >= 7) acc[9][r] = -1e30f;

      float m = acc[0][0];
#pragma unroll
      for (int k2 = 0; k2 < 10; ++k2)
#pragma unroll
        for (int r = 0; r < 4; ++r) m = fmaxf(m, acc[k2][r]);
      m = fmaxf(m, __shfl_xor(m, 16, 64));
      m = fmaxf(m, __shfl_xor(m, 32, 64));
      m = fmaxf(m, mA);                   // final row max
      const float alpha = fexp2(mA - m);  // rescale for phase-A contributions

      float sum = 0.f;
#pragma unroll
      for (int k2 = 0; k2 < 10; ++k2)
#pragma unroll
        for (int r = 0; r < 4; ++r) {
          const float p = fexp2(acc[k2][r] - m);
          acc[k2][r] = p;
          sum += p;
        }
      float lanesum = sumA * alpha + sum;
      lanesum += __shfl_xor(lanesum, 16, 64);
      lanesum += __shfl_xor(lanesum, 32, 64);
      rinv = 1.f / lanesum;

      // rescale o by per-ROW alpha (o rows live at lane c16'=q4*4+r, q4'=0 of same wave)
      float alphar[4];
#pragma unroll
      for (int r = 0; r < 4; ++r) alphar[r] = __shfl(alpha, q4 * 4 + r, 64);
#pragma unroll
      for (int r = 0; r < 4; ++r) {
        o0[r] *= alphar[r];
        o1[r] *= alphar[r];
      }

      // PV-B: ks 6..10 (j 192..351), accumulate into rescaled o
#pragma unroll
      for (int ks = 6; ks < 11; ++ks) {
        const int k2 = 2 * (ks - 6);
        uint4 pw;
        pw.x = pkpair(acc[k2][0], acc[k2][1]);
        pw.y = pkpair(acc[k2][2], acc[k2][3]);
        pw.z = pkpair(acc[k2 + 1][0], acc[k2 + 1][1]);
        pw.w = pkpair(acc[k2 + 1][2], acc[k2 + 1][3]);
        const short8 pf = *reinterpret_cast<const short8*>(&pw);
        const uint2 v0lo = *reinterpret_cast<const uint2*>(&Vt[c16][ks * 32 + q4 * 4]);
        const uint2 v0hi = *reinterpret_cast<const uint2*>(&Vt[c16][ks * 32 + 16 + q4 * 4]);
        const uint2 v1lo = *reinterpret_cast<const uint2*>(&Vt[16 + c16][ks * 32 + q4 * 4]);
        const uint2 v1hi = *reinterpret_cast<const uint2*>(&Vt[16 + c16][ks * 32 + 16 + q4 * 4]);
        uint4 vw0, vw1;
        vw0.x = v0lo.x; vw0.y = v0lo.y; vw0.z = v0hi.x; vw0.w = v0hi.y;
        vw1.x = v1lo.x; vw1.y = v1lo.y; vw1.z = v1hi.x; vw1.w = v1hi.y;
        const short8 v0 = *reinterpret_cast<const short8*>(&vw0);
        const short8 v1 = *reinterpret_cast<const short8*>(&vw1);
        o0 = __builtin_amdgcn_mfma_f32_16x16x32_bf16(pf, v0, o0, 0, 0, 0);
        o1 = __builtin_amdgcn_mfma_f32_16x16x32_bf16(pf, v1, o1, 0, 0, 0);
      }
    }

    // O epilogue: D[row=q4*4+r -> i][col=c16 -> d]; gather 1/sum from row-owner lanes
    float rsv[4];
#pragma unroll
    for (int r = 0; r < 4; ++r) rsv[r] = __shfl(rinv, q4 * 4 + r, 64);
#pragma unroll
    for (int r = 0; r < 4; ++r) {
      const int i = qt * 16 + q4 * 4 + r;
      if (i < NTOK) {
        const size_t ob = ((size_t)s * TOK + (size_t)b * NTOK + i) * DIMC + h * HDIM;
        op[ob + c16]      = f2bf(o0[r] * rsv[r]);
        op[ob + 16 + c16] = f2bf(o1[r] * rsv[r]);
      }
    }
  }
}

// ---------------- output projection: MFMA bf16, 64-row blocks, 3 col-tiles ----------------
__global__ __launch_bounds__(256) void k_proj(const unsigned short* __restrict__ Oin,
                                              const float* __restrict__ w,
                                              const float* __restrict__ pb,
                                              float* __restrict__ out) {
  __shared__ unsigned short Xs[64][200];
  __shared__ unsigned short Ws[64][200];
  const int R0 = blockIdx.x * 64;
  const int tid = threadIdx.x;
  const int lane = tid & 63, wv = tid >> 6;
  const int c16 = lane & 15, q4 = lane >> 4;
  const int wr = wv >> 1, wc = wv & 1;

  for (int c = tid; c < 64 * 24; c += 256) {
    const int r = c / 24, k8 = (c % 24) * 8;
    *reinterpret_cast<uint4*>(&Xs[r][k8]) =
        *reinterpret_cast<const uint4*>(&Oin[(size_t)(R0 + r) * DIMC + k8]);
  }

  for (int ct = 0; ct < 3; ++ct) {
    __syncthreads();
    for (int c = tid; c < 64 * 24; c += 256) {
      const int r = c / 24, k8 = (c % 24) * 8;
      const float* p = &w[(size_t)(ct * 64 + r) * DIMC + k8];
      const float4 a = *reinterpret_cast<const float4*>(p);
      const float4 b = *reinterpret_cast<const float4*>(p + 4);
      *reinterpret_cast<uint4*>(&Ws[r][k8]) = pack8bf(a, b);
    }
    __syncthreads();

    const int colbase = ct * 64 + wc * 32;
    f32x4 acc[2][2];
#pragma unroll
    for (int n = 0; n < 2; ++n) {
      const float bv = pb[colbase + n * 16 + c16];
      acc[0][n] = f32x4{bv, bv, bv, bv};
      acc[1][n] = f32x4{bv, bv, bv, bv};
    }
#pragma unroll
    for (int ks = 0; ks < 6; ++ks) {
      const short8 a0 = *reinterpret_cast<const short8*>(&Xs[wr * 32 + c16][ks * 32 + q4 * 8]);
      const short8 a1 = *reinterpret_cast<const short8*>(&Xs[wr * 32 + 16 + c16][ks * 32 + q4 * 8]);
      const short8 b0 = *reinterpret_cast<const short8*>(&Ws[wc * 32 + c16][ks * 32 + q4 * 8]);
      const short8 b1 = *reinterpret_cast<const short8*>(&Ws[wc * 32 + 16 + c16][ks * 32 + q4 * 8]);
      acc[0][0] = __builtin_amdgcn_mfma_f32_16x16x32_bf16(a0, b0, acc[0][0], 0, 0, 0);
      acc[0][1] = __builtin_amdgcn_mfma_f32_16x16x32_bf16(a0, b1, acc[0][1], 0, 0, 0);
      acc[1][0] = __builtin_amdgcn_mfma_f32_16x16x32_bf16(a1, b0, acc[1][0], 0, 0, 0);
      acc[1][1] = __builtin_amdgcn_mfma_f32_16x16x32_bf16(a1, b1, acc[1][1], 0, 0, 0);
    }

#pragma unroll
    for (int m = 0; m < 2; ++m) {
#pragma unroll
      for (int n = 0; n < 2; ++n) {
        const int col = colbase + n * 16 + c16;
#pragma unroll
        for (int r = 0; r < 4; ++r) {
          const int row = R0 + wr * 32 + m * 16 + q4 * 4 + r;
          out[(size_t)row * DIMC + col] = acc[m][n][r];
        }
      }
    }
  }
}

extern "C" void kernel_launch(void* const* d_in, const int* in_sizes, int n_in,
                              void* d_out, int out_size, void* d_ws, size_t ws_size,
                              hipStream_t stream) {
  const float* x      = (const float*)d_in[0];
  const float* x1     = (const float*)d_in[1];
  const float* qkv_w  = (const float*)d_in[2];
  const float* qkv_b  = (const float*)d_in[3];
  const float* proj_w = (const float*)d_in[4];
  const float* proj_b = (const float*)d_in[5];
  const float* rpb    = (const float*)d_in[6];
  const int*   ridx   = (const int*)d_in[7];
  float* out = (float*)d_out;

  // workspace: qkv bf16 101,154,816 B | O bf16 33,718,272 B | bias f32 (stride 344) 2,831,808 B
  char* ws = (char*)d_ws;
  unsigned short* qkv  = (unsigned short*)ws;
  unsigned short* Ows  = (unsigned short*)(ws + 101154816);
  float*          bws  = (float*)(ws + 101154816 + 33718272);

  k_bias<<<(NN + 255) / 256, 256, 0, stream>>>(rpb, ridx, bws);
  k_qkv<<<M2 / 64, 256, 0, stream>>>(x, x1, qkv_w, qkv_b, qkv);
  k_attn<<<2 * BW * NHEAD, 256, 0, stream>>>((const __hip_bfloat16*)qkv, bws,
                                             (__hip_bfloat16*)Ows);
  k_proj<<<M2 / 64, 256, 0, stream>>>(Ows, proj_w, proj_b, out);
}

// Round 11
// 189.926 us; speedup vs baseline: 19.6586x; 1.0095x over previous
//
#include <hip/hip_runtime.h>
#include <hip/hip_bf16.h>

#define BW 128
#define NTOK 343
#define DIMC 192
#define NHEAD 6
#define HDIM 32
#define TOK (BW * NTOK)      // 43904
#define M2 (2 * TOK)         // 87808
#define NN (NTOK * NTOK)     // 117649
#define BSTR 344             // padded bias row stride (16B-aligned float4 reads)
#define BNN (NTOK * BSTR)    // 117992 per head
#define QSCALE 0.17677669529663687f
#define LOG2E 1.4426950408889634f

typedef unsigned int uint32;
typedef __attribute__((ext_vector_type(8))) short short8;   // 8 bf16 = 4 VGPR
typedef __attribute__((ext_vector_type(4))) float f32x4;

// round-to-nearest-even f32 -> bf16 bits (scalar path)
__device__ __forceinline__ unsigned short f2bf(float f) {
  uint32 u = __float_as_uint(f);
  u += 0x7fffu + ((u >> 16) & 1u);
  return (unsigned short)(u >> 16);
}

// pair pack via v_cvt_pk_bf16_f32 (semantic form; casts beat hand bit-ops)
__device__ __forceinline__ uint32 pkpair(float a, float b) {
  __hip_bfloat162 h = __float22bfloat162_rn(make_float2(a, b));
  uint32 u;
  __builtin_memcpy(&u, &h, 4);
  return u;
}

__device__ __forceinline__ uint4 pack8bf(const float4 a, const float4 b) {
  uint4 pk;
  pk.x = pkpair(a.x, a.y);
  pk.y = pkpair(a.z, a.w);
  pk.z = pkpair(b.x, b.y);
  pk.w = pkpair(b.z, b.w);
  return pk;
}

// native 2^x (v_exp_f32); logits carry log2e factor so this IS softmax's exp
__device__ __forceinline__ float fexp2(float x) {
  float r;
  asm("v_exp_f32 %0, %1" : "=v"(r) : "v"(x));
  return r;
}

// ---------------- bias gather: bias[h][i][j] = rpb[rel_idx[i,j]*NH + h] * log2e ----------------
__global__ void k_bias(const float* __restrict__ rpb, const int* __restrict__ ridx,
                       float* __restrict__ biasws) {
  const int idx = blockIdx.x * 256 + threadIdx.x;
  if (idx < NN) {
    const int r = ridx[idx];
    const int i = idx / NTOK, j = idx % NTOK;
#pragma unroll
    for (int h = 0; h < NHEAD; ++h)
      biasws[h * BNN + i * BSTR + j] = rpb[r * NHEAD + h] * LOG2E;
  }
}

// ---------------- QKV projection: MFMA bf16, swapped operands (token-per-lane D layout) ----------------
// mfma(Wfrag, Xfrag): D[col=c16 -> X row (token)][row=q4*4+r -> W row (out col)].
// Thread owns 1 token x 4 consecutive out-cols -> ushort4 stores; token div/mod hoisted.
__global__ __launch_bounds__(256) void k_qkv(const float* __restrict__ x,
                                             const float* __restrict__ x1,
                                             const float* __restrict__ w,
                                             const float* __restrict__ bvec,
                                             unsigned short* __restrict__ qkvo) {
  __shared__ unsigned short Xs[64][200];
  __shared__ unsigned short Ws[64][200];
  const int R0 = blockIdx.x * 64;
  const int s = R0 / TOK;
  const int tokbase = R0 % TOK;
  const float* __restrict__ src = s ? x1 : x;
  const int tid = threadIdx.x;
  const int lane = tid & 63, wv = tid >> 6;
  const int c16 = lane & 15, q4 = lane >> 4;
  const int wr = wv >> 1, wc = wv & 1;

  // per-thread token info (n-half 0/1), invariant over ct
  const int tok0 = tokbase + wr * 32 + c16;
  const int tok1 = tok0 + 16;
  const int bidx0 = tok0 / NTOK, nn0 = tok0 % NTOK;
  const int bidx1 = tok1 / NTOK, nn1 = tok1 % NTOK;

  for (int c = tid; c < 64 * 24; c += 256) {
    const int r = c / 24, k8 = (c % 24) * 8;
    const float* p = &src[(size_t)(tokbase + r) * DIMC + k8];
    const float4 a = *reinterpret_cast<const float4*>(p);
    const float4 b = *reinterpret_cast<const float4*>(p + 4);
    *reinterpret_cast<uint4*>(&Xs[r][k8]) = pack8bf(a, b);
  }

  for (int ct = 0; ct < 9; ++ct) {
    __syncthreads();
    for (int c = tid; c < 64 * 24; c += 256) {
      const int r = c / 24, k8 = (c % 24) * 8;
      const float* p = &w[(size_t)(ct * 64 + r) * DIMC + k8];
      const float4 a = *reinterpret_cast<const float4*>(p);
      const float4 b = *reinterpret_cast<const float4*>(p + 4);
      *reinterpret_cast<uint4*>(&Ws[r][k8]) = pack8bf(a, b);
    }
    __syncthreads();

    const int colbase = ct * 64 + wc * 32;
    // bias per m-half: 4 consecutive out-cols per thread
    f32x4 acc[2][2];
#pragma unroll
    for (int m = 0; m < 2; ++m) {
      const float4 bb = *reinterpret_cast<const float4*>(&bvec[colbase + m * 16 + q4 * 4]);
      acc[m][0] = f32x4{bb.x, bb.y, bb.z, bb.w};
      acc[m][1] = f32x4{bb.x, bb.y, bb.z, bb.w};
    }
#pragma unroll
    for (int ks = 0; ks < 6; ++ks) {
      const short8 x0 = *reinterpret_cast<const short8*>(&Xs[wr * 32 + c16][ks * 32 + q4 * 8]);
      const short8 x1f = *reinterpret_cast<const short8*>(&Xs[wr * 32 + 16 + c16][ks * 32 + q4 * 8]);
      const short8 w0 = *reinterpret_cast<const short8*>(&Ws[wc * 32 + c16][ks * 32 + q4 * 8]);
      const short8 w1 = *reinterpret_cast<const short8*>(&Ws[wc * 32 + 16 + c16][ks * 32 + q4 * 8]);
      acc[0][0] = __builtin_amdgcn_mfma_f32_16x16x32_bf16(w0, x0, acc[0][0], 0, 0, 0);
      acc[0][1] = __builtin_amdgcn_mfma_f32_16x16x32_bf16(w0, x1f, acc[0][1], 0, 0, 0);
      acc[1][0] = __builtin_amdgcn_mfma_f32_16x16x32_bf16(w1, x0, acc[1][0], 0, 0, 0);
      acc[1][1] = __builtin_amdgcn_mfma_f32_16x16x32_bf16(w1, x1f, acc[1][1], 0, 0, 0);
    }

    // epilogue: 4x ushort4 stores; t uniform per ct (ct/3), Q carries scale*log2e
    const int t = ct / 3;
    const float qs = (t == 0) ? (QSCALE * LOG2E) : 1.0f;
#pragma unroll
    for (int m = 0; m < 2; ++m) {
      const int col0 = colbase + m * 16 + q4 * 4;
      const int h = (col0 - t * DIMC) / HDIM;
      const int d0 = col0 & (HDIM - 1);
      const size_t hb = ((size_t)(s * 3 + t) * BW) * NHEAD + h;  // partial index
#pragma unroll
      for (int n = 0; n < 2; ++n) {
        const int bidx = n ? bidx1 : bidx0;
        const int nn = n ? nn1 : nn0;
        const f32x4 a = acc[m][n];
        uint2 pk;
        pk.x = pkpair((a[0]) * qs, (a[1]) * qs);
        pk.y = pkpair((a[2]) * qs, (a[3]) * qs);
        const size_t ob = ((hb + (size_t)bidx * NHEAD) * NTOK + nn) * HDIM + d0;
        *reinterpret_cast<uint2*>(&qkvo[ob]) = pk;
      }
    }
  }
}

// ---------------- MFMA attention: swapped QK^T + zero-shuffle PV + split-K online softmax ----------------
__global__ __launch_bounds__(256) void k_attn(const __hip_bfloat16* __restrict__ qkvi,
                                              const float* __restrict__ biasws,
                                              __hip_bfloat16* __restrict__ Ows) {
  __shared__ unsigned short Ks[352][40];      // 28160 B
  __shared__ unsigned short Vt[32][360];      // 23040 B, V transposed [d][n]
  const int bid = blockIdx.x;
  const int h = bid / (2 * BW);
  const int sb = bid % (2 * BW);
  const int s = sb >> 7;
  const int b = sb & 127;
  const int so = 1 - s;
  const size_t qbase = (((size_t)(s * 3 + 0) * BW + b) * NHEAD + h) * (size_t)NTOK * HDIM;
  const size_t kbase = (((size_t)(so * 3 + 1) * BW + b) * NHEAD + h) * (size_t)NTOK * HDIM;
  const size_t vbase = (((size_t)(so * 3 + 2) * BW + b) * NHEAD + h) * (size_t)NTOK * HDIM;
  const unsigned short* __restrict__ qp = (const unsigned short*)qkvi;
  unsigned short* __restrict__ op = (unsigned short*)Ows;
  const float* __restrict__ bh = biasws + (size_t)h * BNN;
  const int tid = threadIdx.x;

  for (int idx = tid; idx < 352 * 4; idx += 256) {
    const int n = idx >> 2, d0 = (idx & 3) * 8;
    uint4 v = {0u, 0u, 0u, 0u};
    if (n < NTOK) v = *reinterpret_cast<const uint4*>(qp + kbase + (size_t)n * HDIM + d0);
    *reinterpret_cast<uint4*>(&Ks[n][d0]) = v;
  }
  for (int idx = tid; idx < NTOK * 4; idx += 256) {
    const int n = idx >> 2, d0 = (idx & 3) * 8;
    const uint4 v = *reinterpret_cast<const uint4*>(qp + vbase + (size_t)n * HDIM + d0);
    const unsigned short* ep = reinterpret_cast<const unsigned short*>(&v);
#pragma unroll
    for (int e = 0; e < 8; ++e) Vt[d0 + e][n] = ep[e];
  }
  for (int idx = tid; idx < 32 * 9; idx += 256) Vt[idx / 9][NTOK + idx % 9] = 0;
  __syncthreads();

  const int lane = tid & 63, w = tid >> 6;
  const int c16 = lane & 15, q4 = lane >> 4;
  const bool loSel = (q4 < 2);   // kt=21 bias-load clamp (stay inside row stride)

  for (int qt = w; qt < 22; qt += 4) {
    const int iq = qt * 16 + c16;                     // this lane's softmax row
    const int iqc = (iq < NTOK) ? iq : NTOK - 1;      // clamp (dup rows masked by O-write)
    const short8 qf = *reinterpret_cast<const short8*>(qp + qbase + (size_t)iqc * HDIM + q4 * 8);
    const float* brow = bh + (size_t)iqc * BSTR;

    f32x4 o0 = {0.f, 0.f, 0.f, 0.f}, o1 = {0.f, 0.f, 0.f, 0.f};
    float mA, sumA;   // phase-A row max (cross-lane), per-lane partial sum

    // ================= Phase A: kt 0..11 =================
    {
      f32x4 acc[12];
#pragma unroll
      for (int kt = 0; kt < 12; ++kt) {
        const float4 bv = *reinterpret_cast<const float4*>(brow + kt * 16 + q4 * 4);
        acc[kt] = f32x4{bv.x, bv.y, bv.z, bv.w};
      }
#pragma unroll
      for (int kt = 0; kt < 12; ++kt) {
        const short8 kf = *reinterpret_cast<const short8*>(&Ks[kt * 16 + c16][q4 * 8]);
        acc[kt] = __builtin_amdgcn_mfma_f32_16x16x32_bf16(kf, qf, acc[kt], 0, 0, 0);
      }
      float m = acc[0][0];
#pragma unroll
      for (int kt = 0; kt < 12; ++kt)
#pragma unroll
        for (int r = 0; r < 4; ++r) m = fmaxf(m, acc[kt][r]);
      m = fmaxf(m, __shfl_xor(m, 16, 64));
      m = fmaxf(m, __shfl_xor(m, 32, 64));
      mA = m;
      float sum = 0.f;
#pragma unroll
      for (int kt = 0; kt < 12; ++kt)
#pragma unroll
        for (int r = 0; r < 4; ++r) {
          const float p = fexp2(acc[kt][r] - m);
          acc[kt][r] = p;
          sum += p;
        }
      sumA = sum;   // per-lane partial; cross-lane reduce deferred to phase B

      // PV-A: ks 0..5 (j 0..191)
#pragma unroll
      for (int ks = 0; ks < 6; ++ks) {
        uint4 pw;
        pw.x = pkpair(acc[2 * ks][0], acc[2 * ks][1]);
        pw.y = pkpair(acc[2 * ks][2], acc[2 * ks][3]);
        pw.z = pkpair(acc[2 * ks + 1][0], acc[2 * ks + 1][1]);
        pw.w = pkpair(acc[2 * ks + 1][2], acc[2 * ks + 1][3]);
        const short8 pf = *reinterpret_cast<const short8*>(&pw);
        const uint2 v0lo = *reinterpret_cast<const uint2*>(&Vt[c16][ks * 32 + q4 * 4]);
        const uint2 v0hi = *reinterpret_cast<const uint2*>(&Vt[c16][ks * 32 + 16 + q4 * 4]);
        const uint2 v1lo = *reinterpret_cast<const uint2*>(&Vt[16 + c16][ks * 32 + q4 * 4]);
        const uint2 v1hi = *reinterpret_cast<const uint2*>(&Vt[16 + c16][ks * 32 + 16 + q4 * 4]);
        uint4 vw0, vw1;
        vw0.x = v0lo.x; vw0.y = v0lo.y; vw0.z = v0hi.x; vw0.w = v0hi.y;
        vw1.x = v1lo.x; vw1.y = v1lo.y; vw1.z = v1hi.x; vw1.w = v1hi.y;
        const short8 v0 = *reinterpret_cast<const short8*>(&vw0);
        const short8 v1 = *reinterpret_cast<const short8*>(&vw1);
        o0 = __builtin_amdgcn_mfma_f32_16x16x32_bf16(pf, v0, o0, 0, 0, 0);
        o1 = __builtin_amdgcn_mfma_f32_16x16x32_bf16(pf, v1, o1, 0, 0, 0);
      }
    }

    // ================= Phase B: kt 12..21 =================
    float rinv;
    {
      f32x4 acc[10];
#pragma unroll
      for (int k2 = 0; k2 < 10; ++k2) {
        const int kt = 12 + k2;
        const int jb = (kt < 21) ? (kt * 16 + q4 * 4) : (336 + (loSel ? q4 * 4 : 0));
        const float4 bv = *reinterpret_cast<const float4*>(brow + jb);
        acc[k2] = f32x4{bv.x, bv.y, bv.z, bv.w};
      }
#pragma unroll
      for (int k2 = 0; k2 < 10; ++k2) {
        const short8 kf = *reinterpret_cast<const short8*>(&Ks[(12 + k2) * 16 + c16][q4 * 8]);
        acc[k2] = __builtin_amdgcn_mfma_f32_16x16x32_bf16(kf, qf, acc[k2], 0, 0, 0);
      }
      // mask invalid j: kt=21 -> j = 336 + q4*4 + r >= 343
#pragma unroll
      for (int r = 0; r < 4; ++r)
        if (q4 * 4 + r >= 7) acc[9][r] = -1e30f;

      float m = acc[0][0];
#pragma unroll
      for (int k2 = 0; k2 < 10; ++k2)
#pragma unroll
        for (int r = 0; r < 4; ++r) m = fmaxf(m, acc[k2][r]);
      m = fmaxf(m, __shfl_xor(m, 16, 64));
      m = fmaxf(m, __shfl_xor(m, 32, 64));
      m = fmaxf(m, mA);                   // final row max
      const float alpha = fexp2(mA - m);  // rescale for phase-A contributions

      float sum = 0.f;
#pragma unroll
      for (int k2 = 0; k2 < 10; ++k2)
#pragma unroll
        for (int r = 0; r < 4; ++r) {
          const float p = fexp2(acc[k2][r] - m);
          acc[k2][r] = p;
          sum += p;
        }
      float lanesum = sumA * alpha + sum;
      lanesum += __shfl_xor(lanesum, 16, 64);
      lanesum += __shfl_xor(lanesum, 32, 64);
      rinv = 1.f / lanesum;

      // rescale o by per-ROW alpha
      float alphar[4];
#pragma unroll
      for (int r = 0; r < 4; ++r) alphar[r] = __shfl(alpha, q4 * 4 + r, 64);
#pragma unroll
      for (int r = 0; r < 4; ++r) {
        o0[r] *= alphar[r];
        o1[r] *= alphar[r];
      }

      // PV-B: ks 6..10 (j 192..351), accumulate into rescaled o
#pragma unroll
      for (int ks = 6; ks < 11; ++ks) {
        const int k2 = 2 * (ks - 6);
        uint4 pw;
        pw.x = pkpair(acc[k2][0], acc[k2][1]);
        pw.y = pkpair(acc[k2][2], acc[k2][3]);
        pw.z = pkpair(acc[k2 + 1][0], acc[k2 + 1][1]);
        pw.w = pkpair(acc[k2 + 1][2], acc[k2 + 1][3]);
        const short8 pf = *reinterpret_cast<const short8*>(&pw);
        const uint2 v0lo = *reinterpret_cast<const uint2*>(&Vt[c16][ks * 32 + q4 * 4]);
        const uint2 v0hi = *reinterpret_cast<const uint2*>(&Vt[c16][ks * 32 + 16 + q4 * 4]);
        const uint2 v1lo = *reinterpret_cast<const uint2*>(&Vt[16 + c16][ks * 32 + q4 * 4]);
        const uint2 v1hi = *reinterpret_cast<const uint2*>(&Vt[16 + c16][ks * 32 + 16 + q4 * 4]);
        uint4 vw0, vw1;
        vw0.x = v0lo.x; vw0.y = v0lo.y; vw0.z = v0hi.x; vw0.w = v0hi.y;
        vw1.x = v1lo.x; vw1.y = v1lo.y; vw1.z = v1hi.x; vw1.w = v1hi.y;
        const short8 v0 = *reinterpret_cast<const short8*>(&vw0);
        const short8 v1 = *reinterpret_cast<const short8*>(&vw1);
        o0 = __builtin_amdgcn_mfma_f32_16x16x32_bf16(pf, v0, o0, 0, 0, 0);
        o1 = __builtin_amdgcn_mfma_f32_16x16x32_bf16(pf, v1, o1, 0, 0, 0);
      }
    }

    // O epilogue: D[row=q4*4+r -> i][col=c16 -> d]; gather 1/sum from row-owner lanes
    float rsv[4];
#pragma unroll
    for (int r = 0; r < 4; ++r) rsv[r] = __shfl(rinv, q4 * 4 + r, 64);
#pragma unroll
    for (int r = 0; r < 4; ++r) {
      const int i = qt * 16 + q4 * 4 + r;
      if (i < NTOK) {
        const size_t ob = ((size_t)s * TOK + (size_t)b * NTOK + i) * DIMC + h * HDIM;
        op[ob + c16]      = f2bf(o0[r] * rsv[r]);
        op[ob + 16 + c16] = f2bf(o1[r] * rsv[r]);
      }
    }
  }
}

// ---------------- output projection: MFMA bf16, swapped operands (row-per-lane D layout) ----------------
__global__ __launch_bounds__(256) void k_proj(const unsigned short* __restrict__ Oin,
                                              const float* __restrict__ w,
                                              const float* __restrict__ pb,
                                              float* __restrict__ out) {
  __shared__ unsigned short Xs[64][200];
  __shared__ unsigned short Ws[64][200];
  const int R0 = blockIdx.x * 64;
  const int tid = threadIdx.x;
  const int lane = tid & 63, wv = tid >> 6;
  const int c16 = lane & 15, q4 = lane >> 4;
  const int wr = wv >> 1, wc = wv & 1;

  for (int c = tid; c < 64 * 24; c += 256) {
    const int r = c / 24, k8 = (c % 24) * 8;
    *reinterpret_cast<uint4*>(&Xs[r][k8]) =
        *reinterpret_cast<const uint4*>(&Oin[(size_t)(R0 + r) * DIMC + k8]);
  }

  for (int ct = 0; ct < 3; ++ct) {
    __syncthreads();
    for (int c = tid; c < 64 * 24; c += 256) {
      const int r = c / 24, k8 = (c % 24) * 8;
      const float* p = &w[(size_t)(ct * 64 + r) * DIMC + k8];
      const float4 a = *reinterpret_cast<const float4*>(p);
      const float4 b = *reinterpret_cast<const float4*>(p + 4);
      *reinterpret_cast<uint4*>(&Ws[r][k8]) = pack8bf(a, b);
    }
    __syncthreads();

    const int colbase = ct * 64 + wc * 32;
    f32x4 acc[2][2];
#pragma unroll
    for (int m = 0; m < 2; ++m) {
      const float4 bb = *reinterpret_cast<const float4*>(&pb[colbase + m * 16 + q4 * 4]);
      acc[m][0] = f32x4{bb.x, bb.y, bb.z, bb.w};
      acc[m][1] = f32x4{bb.x, bb.y, bb.z, bb.w};
    }
#pragma unroll
    for (int ks = 0; ks < 6; ++ks) {
      const short8 x0 = *reinterpret_cast<const short8*>(&Xs[wr * 32 + c16][ks * 32 + q4 * 8]);
      const short8 x1f = *reinterpret_cast<const short8*>(&Xs[wr * 32 + 16 + c16][ks * 32 + q4 * 8]);
      const short8 w0 = *reinterpret_cast<const short8*>(&Ws[wc * 32 + c16][ks * 32 + q4 * 8]);
      const short8 w1 = *reinterpret_cast<const short8*>(&Ws[wc * 32 + 16 + c16][ks * 32 + q4 * 8]);
      acc[0][0] = __builtin_amdgcn_mfma_f32_16x16x32_bf16(w0, x0, acc[0][0], 0, 0, 0);
      acc[0][1] = __builtin_amdgcn_mfma_f32_16x16x32_bf16(w0, x1f, acc[0][1], 0, 0, 0);
      acc[1][0] = __builtin_amdgcn_mfma_f32_16x16x32_bf16(w1, x0, acc[1][0], 0, 0, 0);
      acc[1][1] = __builtin_amdgcn_mfma_f32_16x16x32_bf16(w1, x1f, acc[1][1], 0, 0, 0);
    }

    // epilogue: thread owns row (token) x 4 consecutive cols -> float4 stores
#pragma unroll
    for (int m = 0; m < 2; ++m) {
      const int col0 = colbase + m * 16 + q4 * 4;
#pragma unroll
      for (int n = 0; n < 2; ++n) {
        const int row = R0 + wr * 32 + n * 16 + c16;
        float4 ov;
        ov.x = acc[m][n][0];
        ov.y = acc[m][n][1];
        ov.z = acc[m][n][2];
        ov.w = acc[m][n][3];
        *reinterpret_cast<float4*>(&out[(size_t)row * DIMC + col0]) = ov;
      }
    }
  }
}

extern "C" void kernel_launch(void* const* d_in, const int* in_sizes, int n_in,
                              void* d_out, int out_size, void* d_ws, size_t ws_size,
                              hipStream_t stream) {
  const float* x      = (const float*)d_in[0];
  const float* x1     = (const float*)d_in[1];
  const float* qkv_w  = (const float*)d_in[2];
  const float* qkv_b  = (const float*)d_in[3];
  const float* proj_w = (const float*)d_in[4];
  const float* proj_b = (const float*)d_in[5];
  const float* rpb    = (const float*)d_in[6];
  const int*   ridx   = (const int*)d_in[7];
  float* out = (float*)d_out;

  // workspace: qkv bf16 101,154,816 B | O bf16 33,718,272 B | bias f32 (stride 344) 2,831,808 B
  char* ws = (char*)d_ws;
  unsigned short* qkv  = (unsigned short*)ws;
  unsigned short* Ows  = (unsigned short*)(ws + 101154816);
  float*          bws  = (float*)(ws + 101154816 + 33718272);

  k_bias<<<(NN + 255) / 256, 256, 0, stream>>>(rpb, ridx, bws);
  k_qkv<<<M2 / 64, 256, 0, stream>>>(x, x1, qkv_w, qkv_b, qkv);
  k_attn<<<2 * BW * NHEAD, 256, 0, stream>>>((const __hip_bfloat16*)qkv, bws,
                                             (__hip_bfloat16*)Ows);
  k_proj<<<M2 / 64, 256, 0, stream>>>(Ows, proj_w, proj_b, out);
}

// Round 13
// 176.603 us; speedup vs baseline: 21.1416x; 1.0754x over previous
//
#include <hip/hip_runtime.h>
#include <hip/hip_bf16.h>

#define BW 128
#define NTOK 343
#define DIMC 192
#define NHEAD 6
#define HDIM 32
#define TOK (BW * NTOK)      // 43904
#define M2 (2 * TOK)         // 87808
#define NN (NTOK * NTOK)     // 117649
#define BSTR 344             // padded bias row stride (16B-aligned float4 reads)
#define BNN (NTOK * BSTR)    // 117992 per head
#define QSCALE 0.17677669529663687f
#define LOG2E 1.4426950408889634f

typedef unsigned int uint32;
typedef __attribute__((ext_vector_type(8))) short short8;   // 8 bf16 = 4 VGPR
typedef __attribute__((ext_vector_type(4))) float f32x4;

// round-to-nearest-even f32 -> bf16 bits (scalar path)
__device__ __forceinline__ unsigned short f2bf(float f) {
  uint32 u = __float_as_uint(f);
  u += 0x7fffu + ((u >> 16) & 1u);
  return (unsigned short)(u >> 16);
}

// pair pack via v_cvt_pk_bf16_f32 (semantic form; casts beat hand bit-ops)
__device__ __forceinline__ uint32 pkpair(float a, float b) {
  __hip_bfloat162 h = __float22bfloat162_rn(make_float2(a, b));
  uint32 u;
  __builtin_memcpy(&u, &h, 4);
  return u;
}

__device__ __forceinline__ uint4 pack8bf(const float4 a, const float4 b) {
  uint4 pk;
  pk.x = pkpair(a.x, a.y);
  pk.y = pkpair(a.z, a.w);
  pk.z = pkpair(b.x, b.y);
  pk.w = pkpair(b.z, b.w);
  return pk;
}

// native 2^x (v_exp_f32); logits carry log2e factor so this IS softmax's exp
__device__ __forceinline__ float fexp2(float x) {
  float r;
  asm("v_exp_f32 %0, %1" : "=v"(r) : "v"(x));
  return r;
}

// ---------------- bias gather: bias[h][i][j] = rpb[rel_idx[i,j]*NH + h] * log2e ----------------
__global__ void k_bias(const float* __restrict__ rpb, const int* __restrict__ ridx,
                       float* __restrict__ biasws) {
  const int idx = blockIdx.x * 256 + threadIdx.x;
  if (idx < NN) {
    const int r = ridx[idx];
    const int i = idx / NTOK, j = idx % NTOK;
#pragma unroll
    for (int h = 0; h < NHEAD; ++h)
      biasws[h * BNN + i * BSTR + j] = rpb[r * NHEAD + h] * LOG2E;
  }
}

// ---------------- QKV projection: MFMA bf16, BM=128, async W prefetch (T14) ----------------
// mfma(Wfrag, Xfrag): D[col=c16 -> token][row=q4*4+r -> out col]. Wave tile 64x32:
// 8 MFMA per 6 ds_reads per ks. W[ct+1] prefetched to regs during compute of ct.
__global__ __launch_bounds__(256) void k_qkv(const float* __restrict__ x,
                                             const float* __restrict__ x1,
                                             const float* __restrict__ w,
                                             const float* __restrict__ bvec,
                                             unsigned short* __restrict__ qkvo) {
  __shared__ unsigned short Xs[128][200];   // 51.2 KB
  __shared__ unsigned short Ws[64][200];    // 25.6 KB
  const int R0 = blockIdx.x * 128;
  const int s = R0 / TOK;                   // 43904 % 128 == 0, no straddle
  const int tokbase = R0 % TOK;
  const float* __restrict__ src = s ? x1 : x;
  const int tid = threadIdx.x;
  const int lane = tid & 63, wv = tid >> 6;
  const int c16 = lane & 15, q4 = lane >> 4;
  const int wr = wv >> 1, wc = wv & 1;      // wave: 64-row half x 32-col half

  // per-thread token info for the 4 n-subtiles (invariant over ct)
  int bidxv[4], nnv[4];
#pragma unroll
  for (int n = 0; n < 4; ++n) {
    const int tok = tokbase + wr * 64 + n * 16 + c16;
    bidxv[n] = tok / NTOK;
    nnv[n] = tok % NTOK;
  }

  // stage X (f32 -> bf16), 128 rows, each read from HBM exactly once
  for (int c = tid; c < 128 * 24; c += 256) {
    const int r = c / 24, k8 = (c % 24) * 8;
    const float* p = &src[(size_t)(tokbase + r) * DIMC + k8];
    const float4 a = *reinterpret_cast<const float4*>(p);
    const float4 b = *reinterpret_cast<const float4*>(p + 4);
    *reinterpret_cast<uint4*>(&Xs[r][k8]) = pack8bf(a, b);
  }

  // W prefetch registers (6 x 32B per thread)
  float4 wa[6], wb[6];
#pragma unroll
  for (int i = 0; i < 6; ++i) {
    const int c = tid + i * 256;
    const int r = c / 24, k8 = (c % 24) * 8;
    const float* p = &w[(size_t)(0 * 64 + r) * DIMC + k8];
    wa[i] = *reinterpret_cast<const float4*>(p);
    wb[i] = *reinterpret_cast<const float4*>(p + 4);
  }

  for (int ct = 0; ct < 9; ++ct) {
    __syncthreads();   // prev compute done reading Ws (and X-stage visible at ct=0)
#pragma unroll
    for (int i = 0; i < 6; ++i) {
      const int c = tid + i * 256;
      const int r = c / 24, k8 = (c % 24) * 8;
      *reinterpret_cast<uint4*>(&Ws[r][k8]) = pack8bf(wa[i], wb[i]);
    }
    __syncthreads();

    // issue next-tile W loads now; they fly under this ct's MFMAs (T14)
    if (ct < 8) {
#pragma unroll
      for (int i = 0; i < 6; ++i) {
        const int c = tid + i * 256;
        const int r = c / 24, k8 = (c % 24) * 8;
        const float* p = &w[(size_t)((ct + 1) * 64 + r) * DIMC + k8];
        wa[i] = *reinterpret_cast<const float4*>(p);
        wb[i] = *reinterpret_cast<const float4*>(p + 4);
      }
    }

    const int colbase = ct * 64 + wc * 32;
    f32x4 acc[2][4];
#pragma unroll
    for (int m = 0; m < 2; ++m) {
      const float4 bb = *reinterpret_cast<const float4*>(&bvec[colbase + m * 16 + q4 * 4]);
#pragma unroll
      for (int n = 0; n < 4; ++n) acc[m][n] = f32x4{bb.x, bb.y, bb.z, bb.w};
    }
#pragma unroll
    for (int ks = 0; ks < 6; ++ks) {
      const short8 w0 = *reinterpret_cast<const short8*>(&Ws[wc * 32 + c16][ks * 32 + q4 * 8]);
      const short8 w1 = *reinterpret_cast<const short8*>(&Ws[wc * 32 + 16 + c16][ks * 32 + q4 * 8]);
      short8 xf[4];
#pragma unroll
      for (int n = 0; n < 4; ++n)
        xf[n] = *reinterpret_cast<const short8*>(&Xs[wr * 64 + n * 16 + c16][ks * 32 + q4 * 8]);
#pragma unroll
      for (int n = 0; n < 4; ++n) {
        acc[0][n] = __builtin_amdgcn_mfma_f32_16x16x32_bf16(w0, xf[n], acc[0][n], 0, 0, 0);
        acc[1][n] = __builtin_amdgcn_mfma_f32_16x16x32_bf16(w1, xf[n], acc[1][n], 0, 0, 0);
      }
    }

    // epilogue: 8x uint2 stores; t uniform per ct (ct/3), Q carries scale*log2e
    const int t = ct / 3;
    const float qs = (t == 0) ? (QSCALE * LOG2E) : 1.0f;
#pragma unroll
    for (int m = 0; m < 2; ++m) {
      const int col0 = colbase + m * 16 + q4 * 4;
      const int h = (col0 - t * DIMC) / HDIM;
      const int d0 = col0 & (HDIM - 1);
      const size_t hb = ((size_t)(s * 3 + t) * BW) * NHEAD + h;
#pragma unroll
      for (int n = 0; n < 4; ++n) {
        const f32x4 a = acc[m][n];
        uint2 pk;
        pk.x = pkpair(a[0] * qs, a[1] * qs);
        pk.y = pkpair(a[2] * qs, a[3] * qs);
        const size_t ob = ((hb + (size_t)bidxv[n] * NHEAD) * NTOK + nnv[n]) * HDIM + d0;
        *reinterpret_cast<uint2*>(&qkvo[ob]) = pk;
      }
    }
  }
}

// ---------------- MFMA attention: swapped QK^T + zero-shuffle PV + split-K online softmax ----------------
__global__ __launch_bounds__(256) void k_attn(const __hip_bfloat16* __restrict__ qkvi,
                                              const float* __restrict__ biasws,
                                              __hip_bfloat16* __restrict__ Ows) {
  __shared__ unsigned short Ks[352][40];      // 28160 B
  __shared__ unsigned short Vt[32][360];      // 23040 B, V transposed [d][n]
  const int bid = blockIdx.x;
  const int h = bid / (2 * BW);
  const int sb = bid % (2 * BW);
  const int s = sb >> 7;
  const int b = sb & 127;
  const int so = 1 - s;
  const size_t qbase = (((size_t)(s * 3 + 0) * BW + b) * NHEAD + h) * (size_t)NTOK * HDIM;
  const size_t kbase = (((size_t)(so * 3 + 1) * BW + b) * NHEAD + h) * (size_t)NTOK * HDIM;
  const size_t vbase = (((size_t)(so * 3 + 2) * BW + b) * NHEAD + h) * (size_t)NTOK * HDIM;
  const unsigned short* __restrict__ qp = (const unsigned short*)qkvi;
  unsigned short* __restrict__ op = (unsigned short*)Ows;
  const float* __restrict__ bh = biasws + (size_t)h * BNN;
  const int tid = threadIdx.x;

  for (int idx = tid; idx < 352 * 4; idx += 256) {
    const int n = idx >> 2, d0 = (idx & 3) * 8;
    uint4 v = {0u, 0u, 0u, 0u};
    if (n < NTOK) v = *reinterpret_cast<const uint4*>(qp + kbase + (size_t)n * HDIM + d0);
    *reinterpret_cast<uint4*>(&Ks[n][d0]) = v;
  }
  for (int idx = tid; idx < NTOK * 4; idx += 256) {
    const int n = idx >> 2, d0 = (idx & 3) * 8;
    const uint4 v = *reinterpret_cast<const uint4*>(qp + vbase + (size_t)n * HDIM + d0);
    const unsigned short* ep = reinterpret_cast<const unsigned short*>(&v);
#pragma unroll
    for (int e = 0; e < 8; ++e) Vt[d0 + e][n] = ep[e];
  }
  for (int idx = tid; idx < 32 * 9; idx += 256) Vt[idx / 9][NTOK + idx % 9] = 0;
  __syncthreads();

  const int lane = tid & 63, w = tid >> 6;
  const int c16 = lane & 15, q4 = lane >> 4;
  const bool loSel = (q4 < 2);   // kt=21 bias-load clamp (stay inside row stride)

  for (int qt = w; qt < 22; qt += 4) {
    const int iq = qt * 16 + c16;                     // this lane's softmax row
    const int iqc = (iq < NTOK) ? iq : NTOK - 1;      // clamp (dup rows masked by O-write)
    const short8 qf = *reinterpret_cast<const short8*>(qp + qbase + (size_t)iqc * HDIM + q4 * 8);
    const float* brow = bh + (size_t)iqc * BSTR;

    f32x4 o0 = {0.f, 0.f, 0.f, 0.f}, o1 = {0.f, 0.f, 0.f, 0.f};
    float mA, sumA;   // phase-A row max (cross-lane), per-lane partial sum

    // ================= Phase A: kt 0..11 =================
    {
      f32x4 acc[12];
#pragma unroll
      for (int kt = 0; kt < 12; ++kt) {
        const float4 bv = *reinterpret_cast<const float4*>(brow + kt * 16 + q4 * 4);
        acc[kt] = f32x4{bv.x, bv.y, bv.z, bv.w};
      }
#pragma unroll
      for (int kt = 0; kt < 12; ++kt) {
        const short8 kf = *reinterpret_cast<const short8*>(&Ks[kt * 16 + c16][q4 * 8]);
        acc[kt] = __builtin_amdgcn_mfma_f32_16x16x32_bf16(kf, qf, acc[kt], 0, 0, 0);
      }
      float m = acc[0][0];
#pragma unroll
      for (int kt = 0; kt < 12; ++kt)
#pragma unroll
        for (int r = 0; r < 4; ++r) m = fmaxf(m, acc[kt][r]);
      m = fmaxf(m, __shfl_xor(m, 16, 64));
      m = fmaxf(m, __shfl_xor(m, 32, 64));
      mA = m;
      float sum = 0.f;
#pragma unroll
      for (int kt = 0; kt < 12; ++kt)
#pragma unroll
        for (int r = 0; r < 4; ++r) {
          const float p = fexp2(acc[kt][r] - m);
          acc[kt][r] = p;
          sum += p;
        }
      sumA = sum;   // per-lane partial; cross-lane reduce deferred to phase B

      // PV-A: ks 0..5 (j 0..191)
#pragma unroll
      for (int ks = 0; ks < 6; ++ks) {
        uint4 pw;
        pw.x = pkpair(acc[2 * ks][0], acc[2 * ks][1]);
        pw.y = pkpair(acc[2 * ks][2], acc[2 * ks][3]);
        pw.z = pkpair(acc[2 * ks + 1][0], acc[2 * ks + 1][1]);
        pw.w = pkpair(acc[2 * ks + 1][2], acc[2 * ks + 1][3]);
        const short8 pf = *reinterpret_cast<const short8*>(&pw);
        const uint2 v0lo = *reinterpret_cast<const uint2*>(&Vt[c16][ks * 32 + q4 * 4]);
        const uint2 v0hi = *reinterpret_cast<const uint2*>(&Vt[c16][ks * 32 + 16 + q4 * 4]);
        const uint2 v1lo = *reinterpret_cast<const uint2*>(&Vt[16 + c16][ks * 32 + q4 * 4]);
        const uint2 v1hi = *reinterpret_cast<const uint2*>(&Vt[16 + c16][ks * 32 + 16 + q4 * 4]);
        uint4 vw0, vw1;
        vw0.x = v0lo.x; vw0.y = v0lo.y; vw0.z = v0hi.x; vw0.w = v0hi.y;
        vw1.x = v1lo.x; vw1.y = v1lo.y; vw1.z = v1hi.x; vw1.w = v1hi.y;
        const short8 v0 = *reinterpret_cast<const short8*>(&vw0);
        const short8 v1 = *reinterpret_cast<const short8*>(&vw1);
        o0 = __builtin_amdgcn_mfma_f32_16x16x32_bf16(pf, v0, o0, 0, 0, 0);
        o1 = __builtin_amdgcn_mfma_f32_16x16x32_bf16(pf, v1, o1, 0, 0, 0);
      }
    }

    // ================= Phase B: kt 12..21 =================
    float rinv;
    {
      f32x4 acc[10];
#pragma unroll
      for (int k2 = 0; k2 < 10; ++k2) {
        const int kt = 12 + k2;
        const int jb = (kt < 21) ? (kt * 16 + q4 * 4) : (336 + (loSel ? q4 * 4 : 0));
        const float4 bv = *reinterpret_cast<const float4*>(brow + jb);
        acc[k2] = f32x4{bv.x, bv.y, bv.z, bv.w};
      }
#pragma unroll
      for (int k2 = 0; k2 < 10; ++k2) {
        const short8 kf = *reinterpret_cast<const short8*>(&Ks[(12 + k2) * 16 + c16][q4 * 8]);
        acc[k2] = __builtin_amdgcn_mfma_f32_16x16x32_bf16(kf, qf, acc[k2], 0, 0, 0);
      }
      // mask invalid j: kt=21 -> j = 336 + q4*4 + r >= 343
#pragma unroll
      for (int r = 0; r < 4; ++r)
        if (q4 * 4 + r >= 7) acc[9][r] = -1e30f;

      float m = acc[0][0];
#pragma unroll
      for (int k2 = 0; k2 < 10; ++k2)
#pragma unroll
        for (int r = 0; r < 4; ++r) m = fmaxf(m, acc[k2][r]);
      m = fmaxf(m, __shfl_xor(m, 16, 64));
      m = fmaxf(m, __shfl_xor(m, 32, 64));
      m = fmaxf(m, mA);                   // final row max
      const float alpha = fexp2(mA - m);  // rescale for phase-A contributions

      float sum = 0.f;
#pragma unroll
      for (int k2 = 0; k2 < 10; ++k2)
#pragma unroll
        for (int r = 0; r < 4; ++r) {
          const float p = fexp2(acc[k2][r] - m);
          acc[k2][r] = p;
          sum += p;
        }
      float lanesum = sumA * alpha + sum;
      lanesum += __shfl_xor(lanesum, 16, 64);
      lanesum += __shfl_xor(lanesum, 32, 64);
      rinv = 1.f / lanesum;

      // rescale o by per-ROW alpha
      float alphar[4];
#pragma unroll
      for (int r = 0; r < 4; ++r) alphar[r] = __shfl(alpha, q4 * 4 + r, 64);
#pragma unroll
      for (int r = 0; r < 4; ++r) {
        o0[r] *= alphar[r];
        o1[r] *= alphar[r];
      }

      // PV-B: ks 6..10 (j 192..351), accumulate into rescaled o
#pragma unroll
      for (int ks = 6; ks < 11; ++ks) {
        const int k2 = 2 * (ks - 6);
        uint4 pw;
        pw.x = pkpair(acc[k2][0], acc[k2][1]);
        pw.y = pkpair(acc[k2][2], acc[k2][3]);
        pw.z = pkpair(acc[k2 + 1][0], acc[k2 + 1][1]);
        pw.w = pkpair(acc[k2 + 1][2], acc[k2 + 1][3]);
        const short8 pf = *reinterpret_cast<const short8*>(&pw);
        const uint2 v0lo = *reinterpret_cast<const uint2*>(&Vt[c16][ks * 32 + q4 * 4]);
        const uint2 v0hi = *reinterpret_cast<const uint2*>(&Vt[c16][ks * 32 + 16 + q4 * 4]);
        const uint2 v1lo = *reinterpret_cast<const uint2*>(&Vt[16 + c16][ks * 32 + q4 * 4]);
        const uint2 v1hi = *reinterpret_cast<const uint2*>(&Vt[16 + c16][ks * 32 + 16 + q4 * 4]);
        uint4 vw0, vw1;
        vw0.x = v0lo.x; vw0.y = v0lo.y; vw0.z = v0hi.x; vw0.w = v0hi.y;
        vw1.x = v1lo.x; vw1.y = v1lo.y; vw1.z = v1hi.x; vw1.w = v1hi.y;
        const short8 v0 = *reinterpret_cast<const short8*>(&vw0);
        const short8 v1 = *reinterpret_cast<const short8*>(&vw1);
        o0 = __builtin_amdgcn_mfma_f32_16x16x32_bf16(pf, v0, o0, 0, 0, 0);
        o1 = __builtin_amdgcn_mfma_f32_16x16x32_bf16(pf, v1, o1, 0, 0, 0);
      }
    }

    // O epilogue: D[row=q4*4+r -> i][col=c16 -> d]; gather 1/sum from row-owner lanes
    float rsv[4];
#pragma unroll
    for (int r = 0; r < 4; ++r) rsv[r] = __shfl(rinv, q4 * 4 + r, 64);
#pragma unroll
    for (int r = 0; r < 4; ++r) {
      const int i = qt * 16 + q4 * 4 + r;
      if (i < NTOK) {
        const size_t ob = ((size_t)s * TOK + (size_t)b * NTOK + i) * DIMC + h * HDIM;
        op[ob + c16]      = f2bf(o0[r] * rsv[r]);
        op[ob + 16 + c16] = f2bf(o1[r] * rsv[r]);
      }
    }
  }
}

// ---------------- output projection: MFMA bf16, swapped operands (row-per-lane D layout) ----------------
__global__ __launch_bounds__(256) void k_proj(const unsigned short* __restrict__ Oin,
                                              const float* __restrict__ w,
                                              const float* __restrict__ pb,
                                              float* __restrict__ out) {
  __shared__ unsigned short Xs[64][200];
  __shared__ unsigned short Ws[64][200];
  const int R0 = blockIdx.x * 64;
  const int tid = threadIdx.x;
  const int lane = tid & 63, wv = tid >> 6;
  const int c16 = lane & 15, q4 = lane >> 4;
  const int wr = wv >> 1, wc = wv & 1;

  for (int c = tid; c < 64 * 24; c += 256) {
    const int r = c / 24, k8 = (c % 24) * 8;
    *reinterpret_cast<uint4*>(&Xs[r][k8]) =
        *reinterpret_cast<const uint4*>(&Oin[(size_t)(R0 + r) * DIMC + k8]);
  }

  for (int ct = 0; ct < 3; ++ct) {
    __syncthreads();
    for (int c = tid; c < 64 * 24; c += 256) {
      const int r = c / 24, k8 = (c % 24) * 8;
      const float* p = &w[(size_t)(ct * 64 + r) * DIMC + k8];
      const float4 a = *reinterpret_cast<const float4*>(p);
      const float4 b = *reinterpret_cast<const float4*>(p + 4);
      *reinterpret_cast<uint4*>(&Ws[r][k8]) = pack8bf(a, b);
    }
    __syncthreads();

    const int colbase = ct * 64 + wc * 32;
    f32x4 acc[2][2];
#pragma unroll
    for (int m = 0; m < 2; ++m) {
      const float4 bb = *reinterpret_cast<const float4*>(&pb[colbase + m * 16 + q4 * 4]);
      acc[m][0] = f32x4{bb.x, bb.y, bb.z, bb.w};
      acc[m][1] = f32x4{bb.x, bb.y, bb.z, bb.w};
    }
#pragma unroll
    for (int ks = 0; ks < 6; ++ks) {
      const short8 x0 = *reinterpret_cast<const short8*>(&Xs[wr * 32 + c16][ks * 32 + q4 * 8]);
      const short8 x1f = *reinterpret_cast<const short8*>(&Xs[wr * 32 + 16 + c16][ks * 32 + q4 * 8]);
      const short8 w0 = *reinterpret_cast<const short8*>(&Ws[wc * 32 + c16][ks * 32 + q4 * 8]);
      const short8 w1 = *reinterpret_cast<const short8*>(&Ws[wc * 32 + 16 + c16][ks * 32 + q4 * 8]);
      acc[0][0] = __builtin_amdgcn_mfma_f32_16x16x32_bf16(w0, x0, acc[0][0], 0, 0, 0);
      acc[0][1] = __builtin_amdgcn_mfma_f32_16x16x32_bf16(w0, x1f, acc[0][1], 0, 0, 0);
      acc[1][0] = __builtin_amdgcn_mfma_f32_16x16x32_bf16(w1, x0, acc[1][0], 0, 0, 0);
      acc[1][1] = __builtin_amdgcn_mfma_f32_16x16x32_bf16(w1, x1f, acc[1][1], 0, 0, 0);
    }

    // epilogue: thread owns row (token) x 4 consecutive cols -> float4 stores
#pragma unroll
    for (int m = 0; m < 2; ++m) {
      const int col0 = colbase + m * 16 + q4 * 4;
#pragma unroll
      for (int n = 0; n < 2; ++n) {
        const int row = R0 + wr * 32 + n * 16 + c16;
        float4 ov;
        ov.x = acc[m][n][0];
        ov.y = acc[m][n][1];
        ov.z = acc[m][n][2];
        ov.w = acc[m][n][3];
        *reinterpret_cast<float4*>(&out[(size_t)row * DIMC + col0]) = ov;
      }
    }
  }
}

extern "C" void kernel_launch(void* const* d_in, const int* in_sizes, int n_in,
                              void* d_out, int out_size, void* d_ws, size_t ws_size,
                              hipStream_t stream) {
  const float* x      = (const float*)d_in[0];
  const float* x1     = (const float*)d_in[1];
  const float* qkv_w  = (const float*)d_in[2];
  const float* qkv_b  = (const float*)d_in[3];
  const float* proj_w = (const float*)d_in[4];
  const float* proj_b = (const float*)d_in[5];
  const float* rpb    = (const float*)d_in[6];
  const int*   ridx   = (const int*)d_in[7];
  float* out = (float*)d_out;

  // workspace: qkv bf16 101,154,816 B | O bf16 33,718,272 B | bias f32 (stride 344) 2,831,808 B
  char* ws = (char*)d_ws;
  unsigned short* qkv  = (unsigned short*)ws;
  unsigned short* Ows  = (unsigned short*)(ws + 101154816);
  float*          bws  = (float*)(ws + 101154816 + 33718272);

  k_bias<<<(NN + 255) / 256, 256, 0, stream>>>(rpb, ridx, bws);
  k_qkv<<<M2 / 128, 256, 0, stream>>>(x, x1, qkv_w, qkv_b, qkv);
  k_attn<<<2 * BW * NHEAD, 256, 0, stream>>>((const __hip_bfloat16*)qkv, bws,
                                             (__hip_bfloat16*)Ows);
  k_proj<<<M2 / 64, 256, 0, stream>>>(Ows, proj_w, proj_b, out);
}